// Round 12
// baseline (652.902 us; speedup 1.0000x reference)
//
#include <hip/hip_runtime.h>
#include <hip/hip_bf16.h>
#include <hip/hip_cooperative_groups.h>
#include <math.h>

namespace cg = cooperative_groups;

// ---- problem constants ----
static constexpr int NN  = 1024;
static constexpr int KK  = 16;
static constexpr int C0c = 128;
static constexpr int EDc = 64;
static constexpr int Lc  = 2;
static constexpr int ENUM = NN * KK;        // 16384 edges
static constexpr int PL   = NN * 32;        // f32 plane stride
static constexpr int X1HS = NN * 32;        // bf16 x1 plane stride
#define SCALE_ATTN 0.13363062095621219f     /* 1/sqrt(32+3*8) */

typedef __attribute__((ext_vector_type(8))) short s8v;   // 8 bf16
typedef __attribute__((ext_vector_type(4))) float f4v;   // MFMA acc

__device__ __forceinline__ float wsum64(float v) {
    for (int o = 32; o > 0; o >>= 1) v += __shfl_xor(v, o);
    return v;
}
__device__ __forceinline__ float gsum16(float v) {
    for (int o = 8; o > 0; o >>= 1) v += __shfl_xor(v, o, 16);
    return v;
}
__device__ __forceinline__ float gmax16(float v) {
    for (int o = 8; o > 0; o >>= 1) v = fmaxf(v, __shfl_xor(v, o, 16));
    return v;
}
__device__ __forceinline__ float gelu_f(float x) {
    float x3 = x * x * x;
    return 0.5f * x * (1.0f + tanhf(0.7978845608028654f * (x + 0.044715f * x3)));
}
__device__ __forceinline__ unsigned short f2bf(float x) {
    union { float f; unsigned int u; } v; v.f = x;
    unsigned int r = v.u + 0x7fffu + ((v.u >> 16) & 1u);
    return (unsigned short)(r >> 16);
}
__device__ __forceinline__ float bf2f(unsigned short u) {
    union { float f; unsigned int i; } v; v.i = ((unsigned int)u) << 16;
    return v.f;
}
__device__ __forceinline__ s8v ld8(const unsigned short* p) { return *(const s8v*)p; }
__device__ __forceinline__ f4v mfma16(s8v a, s8v b, f4v c) {
    return __builtin_amdgcn_mfma_f32_16x16x32_bf16(a, b, c, 0, 0, 0);
}

struct CvJob { const float* s; unsigned short* d; int n; };
struct CvJobs { CvJob j[20]; int n; int total; };

// =====================================================================
//  setup_kernel: [0,cvb) f32->bf16 cvt | [cvb,cvb+256) kNN | rest f1init
// =====================================================================
__global__ __launch_bounds__(256) void setup_kernel(CvJobs cj, int cvb,
                                                    const float* __restrict__ coords,
                                                    int* __restrict__ idx,
                                                    float* __restrict__ maskf,
                                                    float* __restrict__ y1,
                                                    const float* __restrict__ Wi1,
                                                    float* __restrict__ f1p) {
    __shared__ float ca[NN * 3];
    const int tid = threadIdx.x;
    const int bx = blockIdx.x;
    if (bx < cvb) {
        int g = bx * 256 + tid;
        if (g >= cj.total) return;
        for (int i = 0; i < cj.n; ++i) {
            int n = cj.j[i].n;
            if (g < n) { cj.j[i].d[g] = f2bf(cj.j[i].s[g]); return; }
            g -= n;
        }
        return;
    }
    if (bx < cvb + 256) {
        for (int f = tid; f < NN * 3; f += 256) {
            int i = f / 3, m = f % 3;
            ca[f] = coords[(i * 4 + 1) * 3 + m];
        }
        __syncthreads();
        const int wid = tid >> 6, lane = tid & 63;
        const int n = (bx - cvb) * 4 + wid;
        const float cx = ca[n * 3 + 0], cy = ca[n * 3 + 1], cz = ca[n * 3 + 2];
        float d[16];
#pragma unroll
        for (int s = 0; s < 16; ++s) {
            int i = s * 64 + lane;
            float dx = cx - ca[i * 3 + 0], dy = cy - ca[i * 3 + 1], dz = cz - ca[i * 3 + 2];
            float d2 = dx * dx + dy * dy + dz * dz;
            d[s] = (i == n) ? 1e9f : d2;
        }
        for (int t = 0; t < KK; ++t) {
            float best = 1e30f; int bi = 0;
#pragma unroll
            for (int s = 0; s < 16; ++s) {
                int i = s * 64 + lane;
                float v = d[s];
                if (v < best || (v == best && i < bi)) { best = v; bi = i; }
            }
#pragma unroll
            for (int o = 32; o > 0; o >>= 1) {
                float ov = __shfl_xor(best, o);
                int   oi = __shfl_xor(bi, o);
                if (ov < best || (ov == best && oi < bi)) { best = ov; bi = oi; }
            }
            const int j = bi;
            if (lane == 0) {
                idx[n * KK + t] = j;
                float dist = sqrtf(best);
                maskf[n * KK + t] = (dist <= 16.0f) ? 1.0f : 0.0f;
                float rx = ca[j * 3 + 0] - cx, ry = ca[j * 3 + 1] - cy, rz = ca[j * 3 + 2] - cz;
                float nrm = sqrtf(rx * rx + ry * ry + rz * rz) + 1e-6f;
                y1[(n * KK + t) * 3 + 0] = rx / nrm;
                y1[(n * KK + t) * 3 + 1] = ry / nrm;
                y1[(n * KK + t) * 3 + 2] = rz / nrm;
            }
            const int js = j >> 6, jl = j & 63;
#pragma unroll
            for (int s = 0; s < 16; ++s)
                if (s == js && jl == lane) d[s] = 2e30f;
        }
        return;
    }
    int g = (bx - cvb - 256) * 256 + tid;
    if (g >= NN * 32) return;
    int n = g >> 5, c = g & 31;
    float w0 = Wi1[c * 3 + 0], w1 = Wi1[c * 3 + 1], w2 = Wi1[c * 3 + 2];
#pragma unroll
    for (int m = 0; m < 3; ++m) {
        float cav = coords[(n * 4 + 1) * 3 + m];
        float a0 = coords[(n * 4 + 0) * 3 + m] - cav;
        float a1 = coords[(n * 4 + 2) * 3 + m] - cav;
        float a2 = coords[(n * 4 + 3) * 3 + m] - cav;
        f1p[m * PL + n * 32 + c] = w0 * a0 + w1 * a1 + w2 * a2;
    }
}

// =====================================================================
//  edge_f0_kernel: [0,4096) edge gather+LN | [4096,4128) f0-init MFMA
// =====================================================================
__global__ __launch_bounds__(256) void edge_f0_kernel(const float* __restrict__ pair,
                                                      const int* __restrict__ idx,
                                                      const float* __restrict__ g,
                                                      const float* __restrict__ b,
                                                      unsigned short* __restrict__ edges_h,
                                                      const unsigned short* __restrict__ nf_h,
                                                      const unsigned short* __restrict__ Wi0_h,
                                                      float* __restrict__ f0) {
    const int t = threadIdx.x, wid = t >> 6, lane = t & 63;
    if (blockIdx.x < ENUM / 4) {
        const int e = blockIdx.x * 4 + wid;
        const int n = e >> 4;
        const int j = idx[e];
        float v = pair[((size_t)n * NN + j) * EDc + lane];
        float m = wsum64(v) * (1.0f / 64.0f);
        float d = v - m;
        float var = wsum64(d * d) * (1.0f / 64.0f);
        float nv = d * rsqrtf(var + 1e-5f) * g[lane] + b[lane];
        edges_h[e * EDc + lane] = f2bf(nv);
        return;
    }
    int rel = blockIdx.x - ENUM / 4;
    const int mt = rel & 7, ntc = rel >> 3;
    const int m0 = mt * 128 + wid * 32, n0 = ntc * 32;
    const int c16 = lane & 15, g8 = (lane >> 4) * 8, g4 = (lane >> 4) * 4;
    f4v acc[2][2];
#pragma unroll
    for (int a = 0; a < 2; ++a)
#pragma unroll
        for (int bq = 0; bq < 2; ++bq) acc[a][bq] = f4v{0.f, 0.f, 0.f, 0.f};
    const unsigned short* Ap = nf_h + (size_t)(m0 + c16) * 128 + g8;
    const unsigned short* Bp = Wi0_h + (size_t)(n0 + c16) * 128 + g8;
#pragma unroll
    for (int kc = 0; kc < 128; kc += 32) {
        s8v a0 = ld8(Ap + kc);
        s8v a1 = ld8(Ap + 16 * 128 + kc);
        s8v b0 = ld8(Bp + kc);
        s8v b1 = ld8(Bp + 16 * 128 + kc);
        acc[0][0] = mfma16(a0, b0, acc[0][0]);
        acc[0][1] = mfma16(a0, b1, acc[0][1]);
        acc[1][0] = mfma16(a1, b0, acc[1][0]);
        acc[1][1] = mfma16(a1, b1, acc[1][1]);
    }
#pragma unroll
    for (int fm = 0; fm < 2; ++fm)
#pragma unroll
        for (int r = 0; r < 4; ++r) {
            const int m = m0 + fm * 16 + g4 + r;
#pragma unroll
            for (int fn = 0; fn < 2; ++fn)
                f0[(size_t)m * 128 + n0 + fn * 16 + c16] = acc[fm][fn][r];
        }
}

// ---------------- standalone fiber norm (layer 0 entry) -> bf16 x ----------------
__global__ __launch_bounds__(256) void fnorm1_kernel(const float* __restrict__ f0,
                                                     const float* __restrict__ f1p,
                                                     const float* __restrict__ g0,
                                                     const float* __restrict__ b0,
                                                     const float* __restrict__ g1,
                                                     const float* __restrict__ b1,
                                                     unsigned short* __restrict__ x0h,
                                                     unsigned short* __restrict__ x1h) {
    const int wid = threadIdx.x >> 6, lane = threadIdx.x & 63;
    const int n = blockIdx.x * 4 + wid;
    float va = f0[n * 128 + lane], vb = f0[n * 128 + lane + 64];
    float m = wsum64(va + vb) * (1.0f / 128.0f);
    float da = va - m, db = vb - m;
    float var = wsum64(da * da + db * db) * (1.0f / 128.0f);
    float rs = rsqrtf(var + 1e-5f);
    x0h[n * 128 + lane]      = f2bf(gelu_f(da * rs * g0[lane] + b0[lane]));
    x0h[n * 128 + lane + 64] = f2bf(gelu_f(db * rs * g0[lane + 64] + b0[lane + 64]));
    int c = lane & 31;
    float h0 = f1p[0 * PL + n * 32 + c];
    float h1 = f1p[1 * PL + n * 32 + c];
    float h2 = f1p[2 * PL + n * 32 + c];
    float n1 = sqrtf(h0 * h0 + h1 * h1 + h2 * h2);
    float ms = wsum64(n1) * (1.0f / 64.0f);
    float dd = n1 - ms;
    float vv = wsum64(dd * dd) * (1.0f / 64.0f);
    float sc = gelu_f(dd * rsqrtf(vv + 1e-5f) * g1[c] + b1[c]) / (n1 + 1e-6f);
    if (lane < 32) {
        x1h[0 * X1HS + n * 32 + c] = f2bf(h0 * sc);
        x1h[1 * X1HS + n * 32 + c] = f2bf(h1 * sc);
        x1h[2 * X1HS + n * 32 + c] = f2bf(h2 * sc);
    }
}

// =====================================================================
//  Mega cooperative kernel: per layer {edge_kv | grid.sync | attn |
//  grid.sync | fused_post | grid.sync}.  256 blocks x 512 threads,
//  dynamic LDS 117504 B (1 block/CU).
// =====================================================================
static constexpr int LS_IN0 = 0;
static constexpr int LS_INU = 64 * 168;
static constexpr int LS_INW = LS_INU + 64 * 136;
static constexpr int LS_X0  = LS_INW + 3 * 64 * 104;
static constexpr int LS_X1  = LS_X0 + 64 * 128;
static constexpr int LS_ED  = LS_X1 + 3 * 64 * 32;
static constexpr int LS_Y   = LS_ED + 64 * 72;
static constexpr int EKV_LDS2 = LS_Y * 2 + 64 * 3 * 4;  // 117504

struct MegaArgs {
    const unsigned short *edges_h, *WrK, *WrV, *WkA, *WvA, *WkB, *WvB, *Wb;
    const unsigned short *Wq0, *Wq1, *Wo0, *Wo1, *Wf0a, *Wf0b, *Wf1a, *Wf1b, *Wp0;
    unsigned short *x0h, *x1h;
    const int* idx; const float* y1;
    unsigned short *k0h, *v0h, *uKh, *uVh, *k1ph, *v1ph;
    float *biasb, *q0, *q1p, *f0, *f1p;
    const float *maskf, *alpha_attn, *alpha_ff;
    const float *ln0_g, *ln0_b, *n1_g, *n1_b, *lnf0_g, *lnf0_b, *nf1_g, *nf1_b;
    const float *Wp1, *coords;
    unsigned short *o0h, *o1h;
    float* out;
};

__global__ __launch_bounds__(512) void mega_kernel(MegaArgs A) {
    extern __shared__ unsigned short lsm[];
    cg::grid_group gg = cg::this_grid();
    const int t = threadIdx.x, w = t >> 6, ln = t & 63;
    const int c16 = ln & 15, g8 = (ln >> 4) * 8, g4 = (ln >> 4) * 4;
    const int bid = blockIdx.x;

    for (int l = 0; l < Lc; ++l) {
        const unsigned short* WrKl = A.WrK + (size_t)l * 24576;
        const unsigned short* WrVl = A.WrV + (size_t)l * 24576;
        const unsigned short* WkAl = A.WkA + (size_t)l * 20480;
        const unsigned short* WvAl = A.WvA + (size_t)l * 20480;
        const unsigned short* WkBl = A.WkB + (size_t)l * 7168;
        const unsigned short* WvBl = A.WvB + (size_t)l * 7168;
        const unsigned short* WbLl = A.Wb + (size_t)l * 256;
        const unsigned short* Wq0l = A.Wq0 + (size_t)l * 16384;
        const unsigned short* Wq1l = A.Wq1 + (size_t)l * 1024;

        // ================= EDGE PHASE (all 256 blocks) =================
        {
            unsigned short* in0L = lsm + LS_IN0;
            unsigned short* inUL = lsm + LS_INU;
            unsigned short* inWL = lsm + LS_INW;
            unsigned short* x0L  = lsm + LS_X0;
            unsigned short* x1L  = lsm + LS_X1;
            unsigned short* edL  = lsm + LS_ED;
            float* yL = (float*)(lsm + LS_Y);
            const int e0 = bid * 64;
            for (int c = t; c < 1024; c += 512) {
                int row = c >> 4, sub = c & 15;
                int j = A.idx[e0 + row];
                *(s8v*)&x0L[row * 128 + sub * 8] = ld8(A.x0h + (size_t)j * 128 + sub * 8);
            }
            for (int c = t; c < 768; c += 512) {
                int plane = c >> 8, rem = c & 255;
                int row = rem >> 2, sub = rem & 3;
                int j = A.idx[e0 + row];
                *(s8v*)&x1L[(plane * 64 + row) * 32 + sub * 8] =
                    ld8(A.x1h + (size_t)plane * X1HS + (size_t)j * 32 + sub * 8);
            }
            {
                int row = t >> 3, sub = t & 7;
                *(s8v*)&edL[row * 72 + sub * 8] = ld8(A.edges_h + (size_t)(e0 + row) * 64 + sub * 8);
            }
            if (t < 192) yL[t] = A.y1[e0 * 3 + t];
            __syncthreads();
#pragma unroll 1
            for (int s = 0; s < 2; ++s) {
                const unsigned short* Wr = s ? WrVl : WrKl;
                const unsigned short* WA = s ? WvAl : WkAl;
                const unsigned short* WB = s ? WvBl : WkBl;
                unsigned short* K0o = s ? A.v0h : A.k0h;
                unsigned short* Uo  = s ? A.uVh : A.uKh;
                unsigned short* K1o = s ? A.v1ph : A.k1ph;
#pragma unroll 1
                for (int ti = w; ti < 24; ti += 8) {
                    const int esub = ti & 1, rt = ti >> 1;
                    const int el0 = esub * 32, r0 = rt * 32;
                    f4v acc[2][2];
#pragma unroll
                    for (int a = 0; a < 2; ++a)
#pragma unroll
                        for (int bq = 0; bq < 2; ++bq) acc[a][bq] = f4v{0.f, 0.f, 0.f, 0.f};
#pragma unroll
                    for (int kc = 0; kc < 64; kc += 32) {
                        s8v a0 = *(const s8v*)&edL[(el0 + c16) * 72 + kc + g8];
                        s8v a1 = *(const s8v*)&edL[(el0 + 16 + c16) * 72 + kc + g8];
                        s8v b0 = ld8(Wr + (size_t)(r0 + c16) * 64 + kc + g8);
                        s8v b1 = ld8(Wr + (size_t)(r0 + 16 + c16) * 64 + kc + g8);
                        acc[0][0] = mfma16(a0, b0, acc[0][0]);
                        acc[0][1] = mfma16(a0, b1, acc[0][1]);
                        acc[1][0] = mfma16(a1, b0, acc[1][0]);
                        acc[1][1] = mfma16(a1, b1, acc[1][1]);
                    }
#pragma unroll
                    for (int fm = 0; fm < 2; ++fm)
#pragma unroll
                        for (int r = 0; r < 4; ++r) {
                            const int el = el0 + fm * 16 + g4 + r;
                            float ya = yL[el * 3 + 0], yb = yL[el * 3 + 1], yc = yL[el * 3 + 2];
#pragma unroll
                            for (int fn = 0; fn < 2; ++fn) {
                                const float av = acc[fm][fn][r];
                                const int col = r0 + fn * 16 + c16;
                                if (r0 < 128) {
                                    in0L[el * 168 + col] = f2bf(av * bf2f(x0L[el * 128 + col]));
                                } else if (r0 < 160) {
                                    int c = col - 128;
                                    float d1 = bf2f(x1L[(0 * 64 + el) * 32 + c]) * ya
                                             + bf2f(x1L[(1 * 64 + el) * 32 + c]) * yb
                                             + bf2f(x1L[(2 * 64 + el) * 32 + c]) * yc;
                                    in0L[el * 168 + col] = f2bf(av * d1);
                                } else if (r0 < 288) {
                                    int c = col - 160;
                                    inUL[el * 136 + c] = f2bf(av * bf2f(x0L[el * 128 + c]));
                                } else {
                                    int c = (r0 < 320) ? (col - 288) : (r0 < 352) ? (col - 320) : (col - 352);
                                    float fx = bf2f(x1L[(0 * 64 + el) * 32 + c]);
                                    float fy = bf2f(x1L[(1 * 64 + el) * 32 + c]);
                                    float fz = bf2f(x1L[(2 * 64 + el) * 32 + c]);
                                    float w0, w1, w2; int off;
                                    if (r0 < 320) {
                                        off = 0; w0 = av * fx; w1 = av * fy; w2 = av * fz;
                                    } else if (r0 < 352) {
                                        off = 32;
                                        w0 = av * (fy * yc - fz * yb);
                                        w1 = av * (fz * ya - fx * yc);
                                        w2 = av * (fx * yb - fy * ya);
                                    } else {
                                        off = 64;
                                        float d1 = fx * ya + fy * yb + fz * yc;
                                        w0 = av * (ya * d1 - fx * (1.0f / 3.0f));
                                        w1 = av * (yb * d1 - fy * (1.0f / 3.0f));
                                        w2 = av * (yc * d1 - fz * (1.0f / 3.0f));
                                    }
                                    inWL[0 * 64 * 104 + el * 104 + off + c] = f2bf(w0);
                                    inWL[1 * 64 * 104 + el * 104 + off + c] = f2bf(w1);
                                    inWL[2 * 64 * 104 + el * 104 + off + c] = f2bf(w2);
                                }
                            }
                        }
                }
                __syncthreads();
                const int tmax = (s == 0) ? 18 : 16;
#pragma unroll 1
                for (int ti = w; ti < tmax; ti += 8) {
                    if (ti >= 16) {
                        const int esub = ti - 16;
                        f4v bacc[2] = {f4v{0.f,0.f,0.f,0.f}, f4v{0.f,0.f,0.f,0.f}};
                        s8v zb;
#pragma unroll
                        for (int j = 0; j < 8; ++j) zb[j] = 0;
#pragma unroll
                        for (int kc = 0; kc < 64; kc += 32) {
                            s8v a0 = *(const s8v*)&edL[(esub * 32 + c16) * 72 + kc + g8];
                            s8v a1 = *(const s8v*)&edL[(esub * 32 + 16 + c16) * 72 + kc + g8];
                            s8v b0 = (c16 < 4) ? ld8(WbLl + (size_t)c16 * 64 + kc + g8) : zb;
                            bacc[0] = mfma16(a0, b0, bacc[0]);
                            bacc[1] = mfma16(a1, b0, bacc[1]);
                        }
                        if (c16 < 4) {
#pragma unroll
                            for (int fm = 0; fm < 2; ++fm)
#pragma unroll
                                for (int r = 0; r < 4; ++r)
                                    A.biasb[(size_t)(e0 + esub * 32 + fm * 16 + g4 + r) * 4 + c16] = bacc[fm][r];
                        }
                        continue;
                    }
                    const unsigned short* Ab; const unsigned short* Bb;
                    unsigned short* Cb;
                    int apit, K, ldb, ldcq, esub;
                    if (ti < 8) {
                        esub = ti & 1; int nt = ti >> 1;
                        Ab = in0L; apit = 168; K = 160;
                        Bb = WA + (size_t)(nt * 32) * 160; ldb = 160;
                        Cb = K0o + (size_t)(e0 + esub * 32) * 128 + nt * 32; ldcq = 128;
                    } else if (ti < 10) {
                        esub = ti - 8;
                        Ab = inUL; apit = 136; K = 128; Bb = WB; ldb = 224;
                        Cb = Uo + (size_t)(e0 + esub * 32) * 32; ldcq = 32;
                    } else {
                        int id = ti - 10; int m = id >> 1; esub = id & 1;
                        Ab = inWL + m * 64 * 104; apit = 104; K = 96;
                        Bb = WB + 128; ldb = 224;
                        Cb = K1o + ((size_t)m * ENUM + e0 + esub * 32) * 32; ldcq = 32;
                    }
                    const int m0l = esub * 32;
                    f4v acc[2][2];
#pragma unroll
                    for (int a = 0; a < 2; ++a)
#pragma unroll
                        for (int bq = 0; bq < 2; ++bq) acc[a][bq] = f4v{0.f, 0.f, 0.f, 0.f};
                    for (int kc = 0; kc < K; kc += 32) {
                        s8v a0 = *(const s8v*)&Ab[(m0l + c16) * apit + kc + g8];
                        s8v a1 = *(const s8v*)&Ab[(m0l + 16 + c16) * apit + kc + g8];
                        s8v b0 = ld8(Bb + (size_t)c16 * ldb + kc + g8);
                        s8v b1 = ld8(Bb + (size_t)(16 + c16) * ldb + kc + g8);
                        acc[0][0] = mfma16(a0, b0, acc[0][0]);
                        acc[0][1] = mfma16(a0, b1, acc[0][1]);
                        acc[1][0] = mfma16(a1, b0, acc[1][0]);
                        acc[1][1] = mfma16(a1, b1, acc[1][1]);
                    }
#pragma unroll
                    for (int fm = 0; fm < 2; ++fm)
#pragma unroll
                        for (int r = 0; r < 4; ++r) {
                            const int lr = fm * 16 + g4 + r;
#pragma unroll
                            for (int fn = 0; fn < 2; ++fn)
                                Cb[(size_t)lr * ldcq + fn * 16 + c16] = f2bf(acc[fm][fn][r]);
                        }
                }
                __syncthreads();
            }
            // q projections on blocks 0..27
            if (bid < 28) {
                const int wt = bid * 8 + w;
                const unsigned short* Aq; const unsigned short* Bq;
                float* Cq; int K, lda2, m0, n0, ldc2;
                if (wt < 128) {
                    int rowt = wt >> 2, colt = wt & 3;
                    Aq = A.x0h; Bq = Wq0l; Cq = A.q0;
                    K = 128; lda2 = 128; ldc2 = 128;
                    m0 = rowt * 32; n0 = colt * 32;
                } else {
                    int k = wt - 128;
                    int pl = k >> 5, rowt = k & 31;
                    Aq = A.x1h + (size_t)pl * X1HS; Bq = Wq1l; Cq = A.q1p + (size_t)pl * PL;
                    K = 32; lda2 = 32; ldc2 = 32;
                    m0 = rowt * 32; n0 = 0;
                }
                f4v acc[2][2];
#pragma unroll
                for (int a = 0; a < 2; ++a)
#pragma unroll
                    for (int bq = 0; bq < 2; ++bq) acc[a][bq] = f4v{0.f, 0.f, 0.f, 0.f};
                const unsigned short* Ap = Aq + (size_t)(m0 + c16) * lda2 + g8;
                const unsigned short* Bp = Bq + (size_t)(n0 + c16) * lda2 + g8;
                for (int kc = 0; kc < K; kc += 32) {
                    s8v a0 = ld8(Ap + kc);
                    s8v a1 = ld8(Ap + 16 * lda2 + kc);
                    s8v b0 = ld8(Bp + kc);
                    s8v b1 = ld8(Bp + 16 * lda2 + kc);
                    acc[0][0] = mfma16(a0, b0, acc[0][0]);
                    acc[0][1] = mfma16(a0, b1, acc[0][1]);
                    acc[1][0] = mfma16(a1, b0, acc[1][0]);
                    acc[1][1] = mfma16(a1, b1, acc[1][1]);
                }
#pragma unroll
                for (int fm = 0; fm < 2; ++fm)
#pragma unroll
                    for (int r = 0; r < 4; ++r) {
                        const int m = m0 + fm * 16 + g4 + r;
#pragma unroll
                        for (int fn = 0; fn < 2; ++fn)
                            Cq[(size_t)m * ldc2 + n0 + fn * 16 + c16] = acc[fm][fn][r];
                    }
            }
        }
        __threadfence();
        gg.sync();

        // ================= ATTENTION (blocks 0..127, 1 wave/node) =================
        if (bid < 128) {
            float (*q0s)[128] = (float(*)[128])lsm;
            float (*q1s)[96]  = (float(*)[96])((char*)lsm + 4096);
            float (*attns)[64] = (float(*)[64])((char*)lsm + 7168);
            const int n = bid * 8 + w;
            q0s[w][ln]      = A.q0[n * 128 + ln];
            q0s[w][ln + 64] = A.q0[n * 128 + ln + 64];
            if (ln < 32) {
#pragma unroll
                for (int m = 0; m < 3; ++m) q1s[w][m * 32 + ln] = A.q1p[m * PL + n * 32 + ln];
            }
            {
                const int h = ln >> 4, k = ln & 15;
                const int e = n * KK + k;
                float acc = 0.f;
                const unsigned short* kr = A.k0h + (size_t)e * 128 + h * 32;
#pragma unroll
                for (int c8 = 0; c8 < 4; ++c8) {
                    s8v kv = ld8(kr + c8 * 8);
#pragma unroll
                    for (int j = 0; j < 8; ++j)
                        acc += q0s[w][h * 32 + c8 * 8 + j] * bf2f((unsigned short)kv[j]);
                }
                s8v uv = ld8(A.uKh + (size_t)e * 32 + h * 8);
#pragma unroll
                for (int m = 0; m < 3; ++m) {
                    float yv = A.y1[e * 3 + m];
                    s8v k1v = ld8(A.k1ph + ((size_t)m * ENUM + e) * 32 + h * 8);
#pragma unroll
                    for (int c = 0; c < 8; ++c)
                        acc += q1s[w][m * 32 + h * 8 + c] *
                               (bf2f((unsigned short)k1v[c]) + bf2f((unsigned short)uv[c]) * yv);
                }
                acc = acc * SCALE_ATTN + A.biasb[e * 4 + h];
                if (A.maskf[e] == 0.0f) acc = -1e9f;
                float mx = gmax16(acc);
                float ex = expf(acc - mx);
                float sm = gsum16(ex);
                attns[w][ln] = ex / sm;
            }
            const int g = ln & 15, kq = ln >> 4;
            {
                float o[8] = {};
                const float* aw = &attns[w][(g >> 2) * 16];
#pragma unroll
                for (int kk2 = 0; kk2 < 4; ++kk2) {
                    int kk = kq * 4 + kk2;
                    float a = aw[kk];
                    s8v v = ld8(A.v0h + (size_t)(n * KK + kk) * 128 + g * 8);
#pragma unroll
                    for (int j = 0; j < 8; ++j) o[j] += a * bf2f((unsigned short)v[j]);
                }
#pragma unroll
                for (int j = 0; j < 8; ++j) {
                    o[j] += __shfl_xor(o[j], 16);
                    o[j] += __shfl_xor(o[j], 32);
                }
                if (kq == 0) {
                    s8v r;
#pragma unroll
                    for (int j = 0; j < 8; ++j) r[j] = (short)f2bf(o[j]);
                    *(s8v*)&A.o0h[(size_t)n * 128 + g * 8] = r;
                }
            }
            {
                float o[8] = {};
                const int plane = g >> 2, cg2 = g & 3;
                if (g < 12) {
                    const float* aw = &attns[w][cg2 * 16];
#pragma unroll
                    for (int kk2 = 0; kk2 < 4; ++kk2) {
                        int kk = kq * 4 + kk2;
                        int e2 = n * KK + kk;
                        float a = aw[kk];
                        float yv = A.y1[e2 * 3 + plane];
                        s8v v = ld8(A.v1ph + ((size_t)plane * ENUM + e2) * 32 + cg2 * 8);
                        s8v u = ld8(A.uVh + (size_t)e2 * 32 + cg2 * 8);
#pragma unroll
                        for (int j = 0; j < 8; ++j)
                            o[j] += a * (bf2f((unsigned short)v[j]) + bf2f((unsigned short)u[j]) * yv);
                    }
                }
#pragma unroll
                for (int j = 0; j < 8; ++j) {
                    o[j] += __shfl_xor(o[j], 16);
                    o[j] += __shfl_xor(o[j], 32);
                }
                if (kq == 0 && g < 12) {
                    s8v r;
#pragma unroll
                    for (int j = 0; j < 8; ++j) r[j] = (short)f2bf(o[j]);
                    *(s8v*)&A.o1h[((size_t)plane * NN + n) * 32 + cg2 * 8] = r;
                }
            }
        }
        __threadfence();
        gg.sync();

        // ================= FUSED POST (blocks 0..63, 16 nodes each) =================
        if (bid < 64) {
            const unsigned short* Wo0h = A.Wo0 + (size_t)l * 16384;
            const unsigned short* Wo1h = A.Wo1 + (size_t)l * 1024;
            const unsigned short* Wf0ah = A.Wf0a + (size_t)l * 65536;
            const unsigned short* Wf0bh = A.Wf0b + (size_t)l * 65536;
            const unsigned short* Wf1ah = A.Wf1a + (size_t)l * 4096;
            const unsigned short* Wf1bh = A.Wf1b + (size_t)l * 4096;
            const float* lnf0_g = A.lnf0_g + l * 128;
            const float* lnf0_b = A.lnf0_b + l * 128;
            const float* nf1_g  = A.nf1_g + l * 32;
            const float* nf1_b  = A.nf1_b + l * 32;
            const bool last = (l == Lc - 1);
            float (*f0s)[132] = (float(*)[132])lsm;                                 // 8448
            float (*f1s)[16][36] = (float(*)[16][36])((char*)lsm + 8448);           // 6912
            unsigned short (*x0s)[136] = (unsigned short(*)[136])((char*)lsm + 15360); // 4352
            float (*x1s)[16][36] = (float(*)[16][36])((char*)lsm + 19712);          // 6912
            unsigned short (*hs)[520] = (unsigned short(*)[520])((char*)lsm + 26624);  // 16640
            unsigned short (*h1b)[16][136] = (unsigned short(*)[16][136])((char*)lsm + 43264); // 13056
            const int n0 = bid * 16;
            const float aA = A.alpha_attn[l], aF = A.alpha_ff[l];
            {
                f4v acc = f4v{0.f, 0.f, 0.f, 0.f};
                const unsigned short* Ap = A.o0h + (size_t)(n0 + c16) * 128 + g8;
#pragma unroll
                for (int kc = 0; kc < 128; kc += 32) {
                    s8v a = ld8(Ap + kc);
                    s8v b = ld8(Wo0h + (size_t)(w * 16 + c16) * 128 + g8 + kc);
                    acc = mfma16(a, b, acc);
                }
                int colg = w * 16 + c16;
#pragma unroll
                for (int r = 0; r < 4; ++r) {
                    int row = g4 + r;
                    f0s[row][colg] = A.f0[(size_t)(n0 + row) * 128 + colg] + aA * acc[r];
                }
            }
#pragma unroll
            for (int it = 0; it < 3; ++it) {
                int g = t + it * 512;
                int c = g & 31, node = (g >> 5) & 15, m = g >> 9;
                float a = 0.f;
                const unsigned short* wrow = Wo1h + c * 32;
                const unsigned short* orow = A.o1h + ((size_t)m * NN + n0 + node) * 32;
#pragma unroll
                for (int cc = 0; cc < 32; ++cc) a += bf2f(wrow[cc]) * bf2f(orow[cc]);
                f1s[m][node][c] = A.f1p[(size_t)m * PL + (n0 + node) * 32 + c] + aA * a;
            }
            __syncthreads();
            for (int i = 0; i < 2; ++i) {
                int row = w * 2 + i;
                float v0 = f0s[row][ln], v1 = f0s[row][ln + 64];
                float mn = wsum64(v0 + v1) * (1.0f / 128.0f);
                float d0 = v0 - mn, d1 = v1 - mn;
                float var = wsum64(d0 * d0 + d1 * d1) * (1.0f / 128.0f);
                float rs = rsqrtf(var + 1e-5f);
                x0s[row][ln]      = f2bf(gelu_f(d0 * rs * lnf0_g[ln] + lnf0_b[ln]));
                x0s[row][ln + 64] = f2bf(gelu_f(d1 * rs * lnf0_g[ln + 64] + lnf0_b[ln + 64]));
            }
            if (t < 256) {
                int node = t >> 4, sub = t & 15;
                float p[2][3], n1v[2];
#pragma unroll
                for (int q = 0; q < 2; ++q) {
                    int c = sub + q * 16;
                    p[q][0] = f1s[0][node][c]; p[q][1] = f1s[1][node][c]; p[q][2] = f1s[2][node][c];
                    n1v[q] = sqrtf(p[q][0]*p[q][0] + p[q][1]*p[q][1] + p[q][2]*p[q][2]);
                }
                float s = gsum16(n1v[0] + n1v[1]);
                float mn = s * (1.0f / 32.0f);
                float d0 = n1v[0] - mn, d1 = n1v[1] - mn;
                float vv = gsum16(d0 * d0 + d1 * d1);
                float rs = rsqrtf(vv * (1.0f / 32.0f) + 1e-5f);
#pragma unroll
                for (int q = 0; q < 2; ++q) {
                    int c = sub + q * 16;
                    float sc = gelu_f((n1v[q] - mn) * rs * nf1_g[c] + nf1_b[c]) / (n1v[q] + 1e-6f);
                    x1s[0][node][c] = p[q][0] * sc;
                    x1s[1][node][c] = p[q][1] * sc;
                    x1s[2][node][c] = p[q][2] * sc;
                }
            }
            __syncthreads();
            {
                f4v acc[4];
#pragma unroll
                for (int i = 0; i < 4; ++i) acc[i] = f4v{0.f,0.f,0.f,0.f};
#pragma unroll
                for (int kc = 0; kc < 128; kc += 32) {
                    s8v a = *(const s8v*)&x0s[c16][kc + g8];
#pragma unroll
                    for (int tt = 0; tt < 4; ++tt) {
                        s8v b = ld8(Wf0ah + (size_t)((w * 4 + tt) * 16 + c16) * 128 + g8 + kc);
                        acc[tt] = mfma16(a, b, acc[tt]);
                    }
                }
#pragma unroll
                for (int tt = 0; tt < 4; ++tt) {
                    int colg = (w * 4 + tt) * 16 + c16;
#pragma unroll
                    for (int r = 0; r < 4; ++r) hs[g4 + r][colg] = f2bf(gelu_f(acc[tt][r]));
                }
            }
#pragma unroll
            for (int it = 0; it < 4; ++it) {
                int g = t + it * 512;
                int r = g & 127, node = g >> 7;
                float a0 = 0.f, a1 = 0.f, a2 = 0.f;
                const unsigned short* wrow = Wf1ah + r * 32;
#pragma unroll
                for (int c = 0; c < 32; ++c) {
                    float wv = bf2f(wrow[c]);
                    a0 += wv * x1s[0][node][c];
                    a1 += wv * x1s[1][node][c];
                    a2 += wv * x1s[2][node][c];
                }
                float nh = sqrtf(a0 * a0 + a1 * a1 + a2 * a2);
                float sc = gelu_f(nh) / (nh + 1e-6f);
                h1b[0][node][r] = f2bf(a0 * sc);
                h1b[1][node][r] = f2bf(a1 * sc);
                h1b[2][node][r] = f2bf(a2 * sc);
            }
            __syncthreads();
            {
                f4v acc = f4v{0.f, 0.f, 0.f, 0.f};
#pragma unroll 4
                for (int kc = 0; kc < 512; kc += 32) {
                    s8v a = *(const s8v*)&hs[c16][kc + g8];
                    s8v b = ld8(Wf0bh + (size_t)(w * 16 + c16) * 512 + g8 + kc);
                    acc = mfma16(a, b, acc);
                }
                int colg = w * 16 + c16;
#pragma unroll
                for (int r = 0; r < 4; ++r) {
                    int row = g4 + r;
                    float v = f0s[row][colg] + aF * acc[r];
                    f0s[row][colg] = v;
                    A.f0[(size_t)(n0 + row) * 128 + colg] = v;
                }
            }
#pragma unroll
            for (int it = 0; it < 3; ++it) {
                int g = t + it * 512;
                int c = g & 31, node = (g >> 5) & 15, m = g >> 9;
                float a = 0.f;
                const unsigned short* wrow = Wf1bh + c * 128;
#pragma unroll 8
                for (int r = 0; r < 128; ++r) a += bf2f(wrow[r]) * bf2f(h1b[m][node][r]);
                float v = f1s[m][node][c] + aF * a;
                f1s[m][node][c] = v;
                A.f1p[(size_t)m * PL + (n0 + node) * 32 + c] = v;
            }
            __syncthreads();
            if (!last) {
                const float* ln0n_g = A.ln0_g + 128;
                const float* ln0n_b = A.ln0_b + 128;
                const float* n1n_g  = A.n1_g + 32;
                const float* n1n_b  = A.n1_b + 32;
                for (int i = 0; i < 2; ++i) {
                    int row = w * 2 + i;
                    float v0 = f0s[row][ln], v1 = f0s[row][ln + 64];
                    float mn = wsum64(v0 + v1) * (1.0f / 128.0f);
                    float d0 = v0 - mn, d1 = v1 - mn;
                    float var = wsum64(d0 * d0 + d1 * d1) * (1.0f / 128.0f);
                    float rs = rsqrtf(var + 1e-5f);
                    A.x0h[(size_t)(n0 + row) * 128 + ln]      = f2bf(gelu_f(d0 * rs * ln0n_g[ln] + ln0n_b[ln]));
                    A.x0h[(size_t)(n0 + row) * 128 + ln + 64] = f2bf(gelu_f(d1 * rs * ln0n_g[ln + 64] + ln0n_b[ln + 64]));
                }
                if (t < 256) {
                    int node = t >> 4, sub = t & 15;
                    float p[2][3], n1v[2];
#pragma unroll
                    for (int q = 0; q < 2; ++q) {
                        int c = sub + q * 16;
                        p[q][0] = f1s[0][node][c]; p[q][1] = f1s[1][node][c]; p[q][2] = f1s[2][node][c];
                        n1v[q] = sqrtf(p[q][0]*p[q][0] + p[q][1]*p[q][1] + p[q][2]*p[q][2]);
                    }
                    float s = gsum16(n1v[0] + n1v[1]);
                    float mn = s * (1.0f / 32.0f);
                    float d0 = n1v[0] - mn, d1 = n1v[1] - mn;
                    float vv = gsum16(d0 * d0 + d1 * d1);
                    float rs = rsqrtf(vv * (1.0f / 32.0f) + 1e-5f);
#pragma unroll
                    for (int q = 0; q < 2; ++q) {
                        int c = sub + q * 16;
                        float sc = gelu_f((n1v[q] - mn) * rs * n1n_g[c] + n1n_b[c]) / (n1v[q] + 1e-6f);
                        A.x1h[(size_t)0 * X1HS + (n0 + node) * 32 + c] = f2bf(p[q][0] * sc);
                        A.x1h[(size_t)1 * X1HS + (n0 + node) * 32 + c] = f2bf(p[q][1] * sc);
                        A.x1h[(size_t)2 * X1HS + (n0 + node) * 32 + c] = f2bf(p[q][2] * sc);
                    }
                }
            } else {
#pragma unroll
                for (int it = 0; it < 4; ++it) {
                    int g = t + it * 512;
                    int row = g >> 7, col = g & 127;
                    x0s[row][col] = f2bf(f0s[row][col]);
                }
                __syncthreads();
                f4v acc = f4v{0.f, 0.f, 0.f, 0.f};
#pragma unroll
                for (int kc = 0; kc < 128; kc += 32) {
                    s8v a = *(const s8v*)&x0s[c16][kc + g8];
                    s8v b = ld8(A.Wp0 + (size_t)(w * 16 + c16) * 128 + g8 + kc);
                    acc = mfma16(a, b, acc);
                }
                int colg = w * 16 + c16;
#pragma unroll
                for (int r = 0; r < 4; ++r)
                    A.out[(size_t)(n0 + g4 + r) * 128 + colg] = acc[r];
                if (t < 144) {
                    int node = t / 9, rr = t % 9, o = rr / 3, m = rr % 3;
                    float a = A.coords[((size_t)(n0 + node) * 4 + 1) * 3 + m];
                    for (int c = 0; c < 32; ++c) a += A.Wp1[o * 32 + c] * f1s[m][node][c];
                    A.out[NN * 128 + ((size_t)(n0 + node) * 3 + o) * 3 + m] = a;
                }
            }
        }
        __threadfence();
        gg.sync();
    }
}

extern "C" void kernel_launch(void* const* d_in, const int* in_sizes, int n_in,
                              void* d_out, int out_size, void* d_ws, size_t ws_size,
                              hipStream_t stream) {
    (void)in_sizes; (void)n_in; (void)out_size; (void)ws_size;
    const float* node_feats = (const float*)d_in[0];
    const float* pair       = (const float*)d_in[1];
    const float* coords     = (const float*)d_in[2];
    const float* eln_g      = (const float*)d_in[3];
    const float* eln_b      = (const float*)d_in[4];
    const float* Wi0        = (const float*)d_in[5];
    const float* Wi1        = (const float*)d_in[6];
    const float* ln0_g      = (const float*)d_in[7];
    const float* ln0_b      = (const float*)d_in[8];
    const float* n1_g       = (const float*)d_in[9];
    const float* n1_b       = (const float*)d_in[10];
    const float* Wq0        = (const float*)d_in[11];
    const float* Wq1        = (const float*)d_in[12];
    const float* WrK        = (const float*)d_in[13];
    const float* WrV        = (const float*)d_in[14];
    const float* WkA        = (const float*)d_in[15];
    const float* WkB        = (const float*)d_in[16];
    const float* WvA        = (const float*)d_in[17];
    const float* WvB        = (const float*)d_in[18];
    const float* Wb         = (const float*)d_in[19];
    const float* Wo0        = (const float*)d_in[20];
    const float* Wo1        = (const float*)d_in[21];
    const float* alpha_attn = (const float*)d_in[22];
    const float* lnf0_g     = (const float*)d_in[23];
    const float* lnf0_b     = (const float*)d_in[24];
    const float* nf1_g      = (const float*)d_in[25];
    const float* nf1_b      = (const float*)d_in[26];
    const float* Wf0a       = (const float*)d_in[27];
    const float* Wf0b       = (const float*)d_in[28];
    const float* Wf1a       = (const float*)d_in[29];
    const float* Wf1b       = (const float*)d_in[30];
    const float* alpha_ff   = (const float*)d_in[31];
    const float* Wp0        = (const float*)d_in[32];
    const float* Wp1        = (const float*)d_in[33];
    float* out = (float*)d_out;

    float* ws = (float*)d_ws;
    size_t off = 0;
    int*   idx   = (int*)(ws + off); off += NN * KK;
    float* maskf = ws + off;         off += NN * KK;
    float* y1    = ws + off;         off += NN * KK * 3;
    float* f0    = ws + off;         off += NN * C0c;
    float* f1p   = ws + off;         off += 3 * PL;
    float* q0    = ws + off;         off += NN * C0c;
    float* q1p   = ws + off;         off += 3 * PL;
    float* biasb = ws + off;         off += (size_t)ENUM * 4;
    off = (off + 3) & ~(size_t)3;
    unsigned short* up = (unsigned short*)(ws + off);
    size_t uo = 0;
    unsigned short* edges_h = up + uo; uo += (size_t)ENUM * 64;
    unsigned short* x0h     = up + uo; uo += (size_t)NN * 128;
    unsigned short* x1h     = up + uo; uo += (size_t)3 * X1HS;
    unsigned short* nf_h    = up + uo; uo += (size_t)NN * 128;
    unsigned short* k0h     = up + uo; uo += (size_t)ENUM * 128;
    unsigned short* v0h     = up + uo; uo += (size_t)ENUM * 128;
    unsigned short* uKh     = up + uo; uo += (size_t)ENUM * 32;
    unsigned short* uVh     = up + uo; uo += (size_t)ENUM * 32;
    unsigned short* k1ph    = up + uo; uo += (size_t)3 * ENUM * 32;
    unsigned short* v1ph    = up + uo; uo += (size_t)3 * ENUM * 32;
    unsigned short* o0h     = up + uo; uo += (size_t)NN * 128;
    unsigned short* o1h     = up + uo; uo += (size_t)3 * NN * 32;
    unsigned short* WrK_h   = up + uo; uo += 2 * 24576;
    unsigned short* WrV_h   = up + uo; uo += 2 * 24576;
    unsigned short* WkA_h   = up + uo; uo += 2 * 20480;
    unsigned short* WvA_h   = up + uo; uo += 2 * 20480;
    unsigned short* WkB_h   = up + uo; uo += 2 * 7168;
    unsigned short* WvB_h   = up + uo; uo += 2 * 7168;
    unsigned short* Wq0_h   = up + uo; uo += 2 * 16384;
    unsigned short* Wq1_h   = up + uo; uo += 2 * 1024;
    unsigned short* Wo0_h   = up + uo; uo += 2 * 16384;
    unsigned short* Wo1_h   = up + uo; uo += 2 * 1024;
    unsigned short* Wf0a_h  = up + uo; uo += 2 * 65536;
    unsigned short* Wf0b_h  = up + uo; uo += 2 * 65536;
    unsigned short* Wf1a_h  = up + uo; uo += 2 * 4096;
    unsigned short* Wf1b_h  = up + uo; uo += 2 * 4096;
    unsigned short* Wp0_h   = up + uo; uo += 16384;
    unsigned short* Wi0_h   = up + uo; uo += 16384;
    unsigned short* Wb_h    = up + uo; uo += 2 * 256;

    CvJobs cj; cj.n = 18;
    cj.j[0]  = {WrK,  WrK_h,  2 * 24576};
    cj.j[1]  = {WrV,  WrV_h,  2 * 24576};
    cj.j[2]  = {WkA,  WkA_h,  2 * 20480};
    cj.j[3]  = {WvA,  WvA_h,  2 * 20480};
    cj.j[4]  = {WkB,  WkB_h,  2 * 7168};
    cj.j[5]  = {WvB,  WvB_h,  2 * 7168};
    cj.j[6]  = {Wq0,  Wq0_h,  2 * 16384};
    cj.j[7]  = {Wq1,  Wq1_h,  2 * 1024};
    cj.j[8]  = {Wo0,  Wo0_h,  2 * 16384};
    cj.j[9]  = {Wo1,  Wo1_h,  2 * 1024};
    cj.j[10] = {Wf0a, Wf0a_h, 2 * 65536};
    cj.j[11] = {Wf0b, Wf0b_h, 2 * 65536};
    cj.j[12] = {Wf1a, Wf1a_h, 2 * 4096};
    cj.j[13] = {Wf1b, Wf1b_h, 2 * 4096};
    cj.j[14] = {Wp0,  Wp0_h,  16384};
    cj.j[15] = {Wi0,  Wi0_h,  16384};
    cj.j[16] = {node_feats, nf_h, NN * 128};
    cj.j[17] = {Wb,   Wb_h,   2 * 256};
    cj.total = 2*24576*2 + 2*20480*2 + 2*7168*2 + 2*16384 + 2*1024 + 2*16384
             + 2*1024 + 2*65536*2 + 2*4096*2 + 16384 + 16384 + NN*128 + 2*256;
    const int cvb = (cj.total + 255) / 256;

    setup_kernel<<<cvb + 256 + 128, 256, 0, stream>>>(cj, cvb, coords, idx, maskf, y1, Wi1, f1p);
    edge_f0_kernel<<<ENUM / 4 + 32, 256, 0, stream>>>(pair, idx, eln_g, eln_b,
                                                      edges_h, nf_h, Wi0_h, f0);
    fnorm1_kernel<<<NN / 4, 256, 0, stream>>>(f0, f1p, ln0_g, ln0_b, n1_g, n1_b, x0h, x1h);

    MegaArgs ma;
    ma.edges_h = edges_h; ma.WrK = WrK_h; ma.WrV = WrV_h; ma.WkA = WkA_h; ma.WvA = WvA_h;
    ma.WkB = WkB_h; ma.WvB = WvB_h; ma.Wb = Wb_h;
    ma.Wq0 = Wq0_h; ma.Wq1 = Wq1_h; ma.Wo0 = Wo0_h; ma.Wo1 = Wo1_h;
    ma.Wf0a = Wf0a_h; ma.Wf0b = Wf0b_h; ma.Wf1a = Wf1a_h; ma.Wf1b = Wf1b_h; ma.Wp0 = Wp0_h;
    ma.x0h = x0h; ma.x1h = x1h; ma.idx = idx; ma.y1 = y1;
    ma.k0h = k0h; ma.v0h = v0h; ma.uKh = uKh; ma.uVh = uVh; ma.k1ph = k1ph; ma.v1ph = v1ph;
    ma.biasb = biasb; ma.q0 = q0; ma.q1p = q1p; ma.f0 = f0; ma.f1p = f1p;
    ma.maskf = maskf; ma.alpha_attn = alpha_attn; ma.alpha_ff = alpha_ff;
    ma.ln0_g = ln0_g; ma.ln0_b = ln0_b; ma.n1_g = n1_g; ma.n1_b = n1_b;
    ma.lnf0_g = lnf0_g; ma.lnf0_b = lnf0_b; ma.nf1_g = nf1_g; ma.nf1_b = nf1_b;
    ma.Wp1 = Wp1; ma.coords = coords; ma.o0h = o0h; ma.o1h = o1h; ma.out = out;
    void* kargs[] = { &ma };
    hipLaunchCooperativeKernel((const void*)mega_kernel, dim3(256), dim3(512),
                               kargs, (unsigned)EKV_LDS2, stream);
}

// Round 13
// 218.870 us; speedup vs baseline: 2.9831x; 2.9831x over previous
//
#include <hip/hip_runtime.h>
#include <hip/hip_bf16.h>
#include <math.h>

// ---- problem constants ----
static constexpr int NN  = 1024;
static constexpr int KK  = 16;
static constexpr int C0c = 128;
static constexpr int C1c = 32;
static constexpr int EDc = 64;
static constexpr int Lc  = 2;
static constexpr int ENUM = NN * KK;        // 16384 edges
static constexpr int PL   = NN * C1c;       // f32 plane stride
static constexpr int X1HS = NN * 32;        // bf16 x1 plane stride
#define SCALE_ATTN 0.13363062095621219f     /* 1/sqrt(32+3*8) */

typedef __attribute__((ext_vector_type(8))) short s8v;   // 8 bf16
typedef __attribute__((ext_vector_type(4))) float f4v;   // MFMA acc

__device__ __forceinline__ float wsum64(float v) {
    for (int o = 32; o > 0; o >>= 1) v += __shfl_xor(v, o);
    return v;
}
__device__ __forceinline__ float gsum16(float v) {
    for (int o = 8; o > 0; o >>= 1) v += __shfl_xor(v, o, 16);
    return v;
}
__device__ __forceinline__ float gmax16(float v) {
    for (int o = 8; o > 0; o >>= 1) v = fmaxf(v, __shfl_xor(v, o, 16));
    return v;
}
__device__ __forceinline__ float gelu_f(float x) {
    float x3 = x * x * x;
    return 0.5f * x * (1.0f + tanhf(0.7978845608028654f * (x + 0.044715f * x3)));
}
__device__ __forceinline__ unsigned short f2bf(float x) {
    union { float f; unsigned int u; } v; v.f = x;
    unsigned int r = v.u + 0x7fffu + ((v.u >> 16) & 1u);
    return (unsigned short)(r >> 16);
}
__device__ __forceinline__ float bf2f(unsigned short u) {
    union { float f; unsigned int i; } v; v.i = ((unsigned int)u) << 16;
    return v.f;
}
__device__ __forceinline__ s8v ld8(const unsigned short* p) { return *(const s8v*)p; }
__device__ __forceinline__ f4v mfma16(s8v a, s8v b, f4v c) {
    return __builtin_amdgcn_mfma_f32_16x16x32_bf16(a, b, c, 0, 0, 0);
}

struct CvJob { const float* s; unsigned short* d; int n; };
struct CvJobs { CvJob j[20]; int n; int total; };

// =====================================================================
//  setup_kernel: [0,cvb) f32->bf16 cvt | [cvb,cvb+256) kNN | rest f1init
// =====================================================================
__global__ __launch_bounds__(256) void setup_kernel(CvJobs cj, int cvb,
                                                    const float* __restrict__ coords,
                                                    int* __restrict__ idx,
                                                    float* __restrict__ maskf,
                                                    float* __restrict__ y1,
                                                    const float* __restrict__ Wi1,
                                                    float* __restrict__ f1p) {
    __shared__ float ca[NN * 3];
    const int tid = threadIdx.x;
    const int bx = blockIdx.x;
    if (bx < cvb) {
        int g = bx * 256 + tid;
        if (g >= cj.total) return;
        for (int i = 0; i < cj.n; ++i) {
            int n = cj.j[i].n;
            if (g < n) { cj.j[i].d[g] = f2bf(cj.j[i].s[g]); return; }
            g -= n;
        }
        return;
    }
    if (bx < cvb + 256) {
        for (int f = tid; f < NN * 3; f += 256) {
            int i = f / 3, m = f % 3;
            ca[f] = coords[(i * 4 + 1) * 3 + m];
        }
        __syncthreads();
        const int wid = tid >> 6, lane = tid & 63;
        const int n = (bx - cvb) * 4 + wid;
        const float cx = ca[n * 3 + 0], cy = ca[n * 3 + 1], cz = ca[n * 3 + 2];
        float d[16];
#pragma unroll
        for (int s = 0; s < 16; ++s) {
            int i = s * 64 + lane;
            float dx = cx - ca[i * 3 + 0], dy = cy - ca[i * 3 + 1], dz = cz - ca[i * 3 + 2];
            float d2 = dx * dx + dy * dy + dz * dz;
            d[s] = (i == n) ? 1e9f : d2;
        }
        for (int t = 0; t < KK; ++t) {
            float best = 1e30f; int bi = 0;
#pragma unroll
            for (int s = 0; s < 16; ++s) {
                int i = s * 64 + lane;
                float v = d[s];
                if (v < best || (v == best && i < bi)) { best = v; bi = i; }
            }
#pragma unroll
            for (int o = 32; o > 0; o >>= 1) {
                float ov = __shfl_xor(best, o);
                int   oi = __shfl_xor(bi, o);
                if (ov < best || (ov == best && oi < bi)) { best = ov; bi = oi; }
            }
            const int j = bi;
            if (lane == 0) {
                idx[n * KK + t] = j;
                float dist = sqrtf(best);
                maskf[n * KK + t] = (dist <= 16.0f) ? 1.0f : 0.0f;
                float rx = ca[j * 3 + 0] - cx, ry = ca[j * 3 + 1] - cy, rz = ca[j * 3 + 2] - cz;
                float nrm = sqrtf(rx * rx + ry * ry + rz * rz) + 1e-6f;
                y1[(n * KK + t) * 3 + 0] = rx / nrm;
                y1[(n * KK + t) * 3 + 1] = ry / nrm;
                y1[(n * KK + t) * 3 + 2] = rz / nrm;
            }
            const int js = j >> 6, jl = j & 63;
#pragma unroll
            for (int s = 0; s < 16; ++s)
                if (s == js && jl == lane) d[s] = 2e30f;
        }
        return;
    }
    int g = (bx - cvb - 256) * 256 + tid;
    if (g >= NN * 32) return;
    int n = g >> 5, c = g & 31;
    float w0 = Wi1[c * 3 + 0], w1 = Wi1[c * 3 + 1], w2 = Wi1[c * 3 + 2];
#pragma unroll
    for (int m = 0; m < 3; ++m) {
        float cav = coords[(n * 4 + 1) * 3 + m];
        float a0 = coords[(n * 4 + 0) * 3 + m] - cav;
        float a1 = coords[(n * 4 + 2) * 3 + m] - cav;
        float a2 = coords[(n * 4 + 3) * 3 + m] - cav;
        f1p[m * PL + n * 32 + c] = w0 * a0 + w1 * a1 + w2 * a2;
    }
}

// =====================================================================
//  edge_f0_kernel: [0,4096) edge gather+LN | [4096,4128) f0-init MFMA
// =====================================================================
__global__ __launch_bounds__(256) void edge_f0_kernel(const float* __restrict__ pair,
                                                      const int* __restrict__ idx,
                                                      const float* __restrict__ g,
                                                      const float* __restrict__ b,
                                                      unsigned short* __restrict__ edges_h,
                                                      const unsigned short* __restrict__ nf_h,
                                                      const unsigned short* __restrict__ Wi0_h,
                                                      float* __restrict__ f0) {
    const int t = threadIdx.x, wid = t >> 6, lane = t & 63;
    if (blockIdx.x < ENUM / 4) {
        const int e = blockIdx.x * 4 + wid;
        const int n = e >> 4;
        const int j = idx[e];
        float v = pair[((size_t)n * NN + j) * EDc + lane];
        float m = wsum64(v) * (1.0f / 64.0f);
        float d = v - m;
        float var = wsum64(d * d) * (1.0f / 64.0f);
        float nv = d * rsqrtf(var + 1e-5f) * g[lane] + b[lane];
        edges_h[e * EDc + lane] = f2bf(nv);
        return;
    }
    int rel = blockIdx.x - ENUM / 4;
    const int mt = rel & 7, ntc = rel >> 3;
    const int m0 = mt * 128 + wid * 32, n0 = ntc * 32;
    const int c16 = lane & 15, g8 = (lane >> 4) * 8, g4 = (lane >> 4) * 4;
    f4v acc[2][2];
#pragma unroll
    for (int a = 0; a < 2; ++a)
#pragma unroll
        for (int bq = 0; bq < 2; ++bq) acc[a][bq] = f4v{0.f, 0.f, 0.f, 0.f};
    const unsigned short* Ap = nf_h + (size_t)(m0 + c16) * 128 + g8;
    const unsigned short* Bp = Wi0_h + (size_t)(n0 + c16) * 128 + g8;
#pragma unroll
    for (int kc = 0; kc < 128; kc += 32) {
        s8v a0 = ld8(Ap + kc);
        s8v a1 = ld8(Ap + 16 * 128 + kc);
        s8v b0 = ld8(Bp + kc);
        s8v b1 = ld8(Bp + 16 * 128 + kc);
        acc[0][0] = mfma16(a0, b0, acc[0][0]);
        acc[0][1] = mfma16(a0, b1, acc[0][1]);
        acc[1][0] = mfma16(a1, b0, acc[1][0]);
        acc[1][1] = mfma16(a1, b1, acc[1][1]);
    }
#pragma unroll
    for (int fm = 0; fm < 2; ++fm)
#pragma unroll
        for (int r = 0; r < 4; ++r) {
            const int m = m0 + fm * 16 + g4 + r;
#pragma unroll
            for (int fn = 0; fn < 2; ++fn)
                f0[(size_t)m * 128 + n0 + fn * 16 + c16] = acc[fm][fn][r];
        }
}

// ---------------- standalone fiber norm (layer 0 entry) -> bf16 x ----------------
__global__ __launch_bounds__(256) void fnorm1_kernel(const float* __restrict__ f0,
                                                     const float* __restrict__ f1p,
                                                     const float* __restrict__ g0,
                                                     const float* __restrict__ b0,
                                                     const float* __restrict__ g1,
                                                     const float* __restrict__ b1,
                                                     unsigned short* __restrict__ x0h,
                                                     unsigned short* __restrict__ x1h) {
    const int wid = threadIdx.x >> 6, lane = threadIdx.x & 63;
    const int n = blockIdx.x * 4 + wid;
    float va = f0[n * 128 + lane], vb = f0[n * 128 + lane + 64];
    float m = wsum64(va + vb) * (1.0f / 128.0f);
    float da = va - m, db = vb - m;
    float var = wsum64(da * da + db * db) * (1.0f / 128.0f);
    float rs = rsqrtf(var + 1e-5f);
    x0h[n * 128 + lane]      = f2bf(gelu_f(da * rs * g0[lane] + b0[lane]));
    x0h[n * 128 + lane + 64] = f2bf(gelu_f(db * rs * g0[lane + 64] + b0[lane + 64]));
    int c = lane & 31;
    float h0 = f1p[0 * PL + n * 32 + c];
    float h1 = f1p[1 * PL + n * 32 + c];
    float h2 = f1p[2 * PL + n * 32 + c];
    float n1 = sqrtf(h0 * h0 + h1 * h1 + h2 * h2);
    float ms = wsum64(n1) * (1.0f / 64.0f);
    float dd = n1 - ms;
    float vv = wsum64(dd * dd) * (1.0f / 64.0f);
    float sc = gelu_f(dd * rsqrtf(vv + 1e-5f) * g1[c] + b1[c]) / (n1 + 1e-6f);
    if (lane < 32) {
        x1h[0 * X1HS + n * 32 + c] = f2bf(h0 * sc);
        x1h[1 * X1HS + n * 32 + c] = f2bf(h1 * sc);
        x1h[2 * X1HS + n * 32 + c] = f2bf(h2 * sc);
    }
}

// =====================================================================
//  edge_kv2: 512-thread blocks.  bid<256: K then V for one 64-edge tile
//  (radial MFMA + epilogue into LDS, then k0/u/k1 GEMMs + bias tile),
//  with gathered x0/x1/y AND the edge tile staged in LDS.
//  bid>=256: q projections.
//  LDS (shorts): in0L[64][168] | inUL[64][136] | inWL[3][64][104] |
//                x0L[64][128] | x1L[3][64][32] | edL[64][72] | yL f32[64][3]
// =====================================================================
static constexpr int LS_IN0 = 0;
static constexpr int LS_INU = 64 * 168;
static constexpr int LS_INW = LS_INU + 64 * 136;
static constexpr int LS_X0  = LS_INW + 3 * 64 * 104;
static constexpr int LS_X1  = LS_X0 + 64 * 128;
static constexpr int LS_ED  = LS_X1 + 3 * 64 * 32;
static constexpr int LS_Y   = LS_ED + 64 * 72;          // shorts offset (even)
static constexpr int EKV_LDS2 = LS_Y * 2 + 64 * 3 * 4;  // 116736 + 768 = 117504

__global__ __launch_bounds__(512) void edge_kv2(
    const unsigned short* __restrict__ edges_h,
    const unsigned short* __restrict__ WrK, const unsigned short* __restrict__ WrV,
    const unsigned short* __restrict__ WkA, const unsigned short* __restrict__ WvA,
    const unsigned short* __restrict__ WkB, const unsigned short* __restrict__ WvB,
    const unsigned short* __restrict__ WbL,
    const unsigned short* __restrict__ x0h, const unsigned short* __restrict__ x1h,
    const int* __restrict__ idx, const float* __restrict__ y1,
    unsigned short* __restrict__ k0h, unsigned short* __restrict__ v0h,
    unsigned short* __restrict__ uKh, unsigned short* __restrict__ uVh,
    unsigned short* __restrict__ k1ph, unsigned short* __restrict__ v1ph,
    float* __restrict__ biasb,
    const unsigned short* __restrict__ Wq0l, const unsigned short* __restrict__ Wq1l,
    float* __restrict__ q0, float* __restrict__ q1p) {
    extern __shared__ unsigned short lsm[];
    const int t = threadIdx.x, w = t >> 6, l = t & 63;
    const int c16 = l & 15, g8 = (l >> 4) * 8, g4 = (l >> 4) * 4;
    const int bid = blockIdx.x;
    if (bid < 256) {
        unsigned short* in0L = lsm + LS_IN0;
        unsigned short* inUL = lsm + LS_INU;
        unsigned short* inWL = lsm + LS_INW;
        unsigned short* x0L  = lsm + LS_X0;
        unsigned short* x1L  = lsm + LS_X1;
        unsigned short* edL  = lsm + LS_ED;
        float* yL = (float*)(lsm + LS_Y);
        const int e0 = bid * 64;
        // ---- stage gathered x0/x1/y + edge tile into LDS ----
        for (int c = t; c < 1024; c += 512) {
            int row = c >> 4, sub = c & 15;
            int j = idx[e0 + row];
            *(s8v*)&x0L[row * 128 + sub * 8] = ld8(x0h + (size_t)j * 128 + sub * 8);
        }
        for (int c = t; c < 768; c += 512) {
            int plane = c >> 8, rem = c & 255;
            int row = rem >> 2, sub = rem & 3;
            int j = idx[e0 + row];
            *(s8v*)&x1L[(plane * 64 + row) * 32 + sub * 8] =
                ld8(x1h + (size_t)plane * X1HS + (size_t)j * 32 + sub * 8);
        }
        for (int c = t; c < 512; c += 512) {
            int row = c >> 3, sub = c & 7;
            *(s8v*)&edL[row * 72 + sub * 8] = ld8(edges_h + (size_t)(e0 + row) * 64 + sub * 8);
        }
        if (t < 192) yL[t] = y1[e0 * 3 + t];
        __syncthreads();
#pragma unroll 1
        for (int s = 0; s < 2; ++s) {
            const unsigned short* Wr = s ? WrV : WrK;
            const unsigned short* WA = s ? WvA : WkA;
            const unsigned short* WB = s ? WvB : WkB;
            unsigned short* K0o = s ? v0h : k0h;
            unsigned short* Uo  = s ? uVh : uKh;
            unsigned short* K1o = s ? v1ph : k1ph;
            // ---- phase A: radial MFMA (edges from LDS) + epilogue into LDS ----
#pragma unroll 1
            for (int ti = w; ti < 24; ti += 8) {
                const int esub = ti & 1, rt = ti >> 1;
                const int el0 = esub * 32, r0 = rt * 32;
                f4v acc[2][2];
#pragma unroll
                for (int a = 0; a < 2; ++a)
#pragma unroll
                    for (int bq = 0; bq < 2; ++bq) acc[a][bq] = f4v{0.f, 0.f, 0.f, 0.f};
#pragma unroll
                for (int kc = 0; kc < 64; kc += 32) {
                    s8v a0 = *(const s8v*)&edL[(el0 + c16) * 72 + kc + g8];
                    s8v a1 = *(const s8v*)&edL[(el0 + 16 + c16) * 72 + kc + g8];
                    s8v b0 = ld8(Wr + (size_t)(r0 + c16) * 64 + kc + g8);
                    s8v b1 = ld8(Wr + (size_t)(r0 + 16 + c16) * 64 + kc + g8);
                    acc[0][0] = mfma16(a0, b0, acc[0][0]);
                    acc[0][1] = mfma16(a0, b1, acc[0][1]);
                    acc[1][0] = mfma16(a1, b0, acc[1][0]);
                    acc[1][1] = mfma16(a1, b1, acc[1][1]);
                }
#pragma unroll
                for (int fm = 0; fm < 2; ++fm)
#pragma unroll
                    for (int r = 0; r < 4; ++r) {
                        const int el = el0 + fm * 16 + g4 + r;
                        float ya = yL[el * 3 + 0], yb = yL[el * 3 + 1], yc = yL[el * 3 + 2];
#pragma unroll
                        for (int fn = 0; fn < 2; ++fn) {
                            const float av = acc[fm][fn][r];
                            const int col = r0 + fn * 16 + c16;
                            if (r0 < 128) {
                                in0L[el * 168 + col] = f2bf(av * bf2f(x0L[el * 128 + col]));
                            } else if (r0 < 160) {
                                int c = col - 128;
                                float d1 = bf2f(x1L[(0 * 64 + el) * 32 + c]) * ya
                                         + bf2f(x1L[(1 * 64 + el) * 32 + c]) * yb
                                         + bf2f(x1L[(2 * 64 + el) * 32 + c]) * yc;
                                in0L[el * 168 + col] = f2bf(av * d1);
                            } else if (r0 < 288) {
                                int c = col - 160;
                                inUL[el * 136 + c] = f2bf(av * bf2f(x0L[el * 128 + c]));
                            } else {
                                int c = (r0 < 320) ? (col - 288) : (r0 < 352) ? (col - 320) : (col - 352);
                                float fx = bf2f(x1L[(0 * 64 + el) * 32 + c]);
                                float fy = bf2f(x1L[(1 * 64 + el) * 32 + c]);
                                float fz = bf2f(x1L[(2 * 64 + el) * 32 + c]);
                                float w0, w1, w2; int off;
                                if (r0 < 320) {
                                    off = 0; w0 = av * fx; w1 = av * fy; w2 = av * fz;
                                } else if (r0 < 352) {
                                    off = 32;
                                    w0 = av * (fy * yc - fz * yb);
                                    w1 = av * (fz * ya - fx * yc);
                                    w2 = av * (fx * yb - fy * ya);
                                } else {
                                    off = 64;
                                    float d1 = fx * ya + fy * yb + fz * yc;
                                    w0 = av * (ya * d1 - fx * (1.0f / 3.0f));
                                    w1 = av * (yb * d1 - fy * (1.0f / 3.0f));
                                    w2 = av * (yc * d1 - fz * (1.0f / 3.0f));
                                }
                                inWL[0 * 64 * 104 + el * 104 + off + c] = f2bf(w0);
                                inWL[1 * 64 * 104 + el * 104 + off + c] = f2bf(w1);
                                inWL[2 * 64 * 104 + el * 104 + off + c] = f2bf(w2);
                            }
                        }
                    }
            }
            __syncthreads();
            // ---- phase B: k0 / u / k1 GEMMs (+ bias tiles when s==0) ----
            const int tmax = (s == 0) ? 18 : 16;
#pragma unroll 1
            for (int ti = w; ti < tmax; ti += 8) {
                if (ti >= 16) {
                    // bias tile: biasb[e][h] = edges[e] . WbL[h]  (h<4)
                    const int esub = ti - 16;
                    f4v bacc[2] = {f4v{0.f,0.f,0.f,0.f}, f4v{0.f,0.f,0.f,0.f}};
                    s8v zb;
#pragma unroll
                    for (int j = 0; j < 8; ++j) zb[j] = 0;
#pragma unroll
                    for (int kc = 0; kc < 64; kc += 32) {
                        s8v a0 = *(const s8v*)&edL[(esub * 32 + c16) * 72 + kc + g8];
                        s8v a1 = *(const s8v*)&edL[(esub * 32 + 16 + c16) * 72 + kc + g8];
                        s8v b0 = (c16 < 4) ? ld8(WbL + (size_t)c16 * 64 + kc + g8) : zb;
                        bacc[0] = mfma16(a0, b0, bacc[0]);
                        bacc[1] = mfma16(a1, b0, bacc[1]);
                    }
                    if (c16 < 4) {
#pragma unroll
                        for (int fm = 0; fm < 2; ++fm)
#pragma unroll
                            for (int r = 0; r < 4; ++r)
                                biasb[(size_t)(e0 + esub * 32 + fm * 16 + g4 + r) * 4 + c16] = bacc[fm][r];
                    }
                    continue;
                }
                const unsigned short* Ab; const unsigned short* Bb;
                unsigned short* Cb;
                int apit, K, ldb, ldcq, esub;
                if (ti < 8) {
                    esub = ti & 1; int nt = ti >> 1;
                    Ab = in0L; apit = 168; K = 160;
                    Bb = WA + (size_t)(nt * 32) * 160; ldb = 160;
                    Cb = K0o + (size_t)(e0 + esub * 32) * 128 + nt * 32; ldcq = 128;
                } else if (ti < 10) {
                    esub = ti - 8;
                    Ab = inUL; apit = 136; K = 128; Bb = WB; ldb = 224;
                    Cb = Uo + (size_t)(e0 + esub * 32) * 32; ldcq = 32;
                } else {
                    int id = ti - 10; int m = id >> 1; esub = id & 1;
                    Ab = inWL + m * 64 * 104; apit = 104; K = 96;
                    Bb = WB + 128; ldb = 224;
                    Cb = K1o + ((size_t)m * ENUM + e0 + esub * 32) * 32; ldcq = 32;
                }
                const int m0l = esub * 32;
                f4v acc[2][2];
#pragma unroll
                for (int a = 0; a < 2; ++a)
#pragma unroll
                    for (int bq = 0; bq < 2; ++bq) acc[a][bq] = f4v{0.f, 0.f, 0.f, 0.f};
                for (int kc = 0; kc < K; kc += 32) {
                    s8v a0 = *(const s8v*)&Ab[(m0l + c16) * apit + kc + g8];
                    s8v a1 = *(const s8v*)&Ab[(m0l + 16 + c16) * apit + kc + g8];
                    s8v b0 = ld8(Bb + (size_t)c16 * ldb + kc + g8);
                    s8v b1 = ld8(Bb + (size_t)(16 + c16) * ldb + kc + g8);
                    acc[0][0] = mfma16(a0, b0, acc[0][0]);
                    acc[0][1] = mfma16(a0, b1, acc[0][1]);
                    acc[1][0] = mfma16(a1, b0, acc[1][0]);
                    acc[1][1] = mfma16(a1, b1, acc[1][1]);
                }
#pragma unroll
                for (int fm = 0; fm < 2; ++fm)
#pragma unroll
                    for (int r = 0; r < 4; ++r) {
                        const int lr = fm * 16 + g4 + r;
#pragma unroll
                        for (int fn = 0; fn < 2; ++fn)
                            Cb[(size_t)lr * ldcq + fn * 16 + c16] = f2bf(acc[fm][fn][r]);
                    }
            }
            __syncthreads();   // protect in-buffers before V overwrites them
        }
        return;
    }
    // ---- q path: 28 blocks x 8 wave-tiles = 224 tiles ----
    const int wt = (bid - 256) * 8 + w;
    const unsigned short* A; const unsigned short* B;
    float* C; int K, lda2, m0, n0, ldc2;
    if (wt < 128) {
        int rowt = wt >> 2, colt = wt & 3;
        A = x0h; B = Wq0l; C = q0;
        K = 128; lda2 = 128; ldc2 = 128;
        m0 = rowt * 32; n0 = colt * 32;
    } else {
        int k = wt - 128;
        int pl = k >> 5, rowt = k & 31;
        A = x1h + (size_t)pl * X1HS; B = Wq1l; C = q1p + (size_t)pl * PL;
        K = 32; lda2 = 32; ldc2 = 32;
        m0 = rowt * 32; n0 = 0;
    }
    f4v acc[2][2];
#pragma unroll
    for (int a = 0; a < 2; ++a)
#pragma unroll
        for (int bq = 0; bq < 2; ++bq) acc[a][bq] = f4v{0.f, 0.f, 0.f, 0.f};
    const unsigned short* Ap = A + (size_t)(m0 + c16) * lda2 + g8;
    const unsigned short* Bp = B + (size_t)(n0 + c16) * lda2 + g8;
    for (int kc = 0; kc < K; kc += 32) {
        s8v a0 = ld8(Ap + kc);
        s8v a1 = ld8(Ap + 16 * lda2 + kc);
        s8v b0 = ld8(Bp + kc);
        s8v b1 = ld8(Bp + 16 * lda2 + kc);
        acc[0][0] = mfma16(a0, b0, acc[0][0]);
        acc[0][1] = mfma16(a0, b1, acc[0][1]);
        acc[1][0] = mfma16(a1, b0, acc[1][0]);
        acc[1][1] = mfma16(a1, b1, acc[1][1]);
    }
#pragma unroll
    for (int fm = 0; fm < 2; ++fm)
#pragma unroll
        for (int r = 0; r < 4; ++r) {
            const int m = m0 + fm * 16 + g4 + r;
#pragma unroll
            for (int fn = 0; fn < 2; ++fn)
                C[(size_t)m * ldc2 + n0 + fn * 16 + c16] = acc[fm][fn][r];
        }
}

// ---------------- attention core (vectorized v-loads; shfl-reduced o) ----------------
__global__ __launch_bounds__(256) void attn_core(const float* __restrict__ q0,
                                                 const float* __restrict__ q1p,
                                                 const unsigned short* __restrict__ k0h,
                                                 const unsigned short* __restrict__ k1ph,
                                                 const unsigned short* __restrict__ v0h,
                                                 const unsigned short* __restrict__ v1ph,
                                                 const unsigned short* __restrict__ uKh,
                                                 const unsigned short* __restrict__ uVh,
                                                 const float* __restrict__ biasb,
                                                 const float* __restrict__ maskf,
                                                 const float* __restrict__ y1,
                                                 unsigned short* __restrict__ o0h,
                                                 unsigned short* __restrict__ o1h) {
    __shared__ float q0s[4][128];
    __shared__ float q1s[4][96];
    __shared__ float attns[4][64];
    const int wid = threadIdx.x >> 6, lane = threadIdx.x & 63;
    const int n = blockIdx.x * 4 + wid;
    q0s[wid][lane]      = q0[n * 128 + lane];
    q0s[wid][lane + 64] = q0[n * 128 + lane + 64];
    if (lane < 32) {
#pragma unroll
        for (int m = 0; m < 3; ++m) q1s[wid][m * 32 + lane] = q1p[m * PL + n * 32 + lane];
    }
    __syncthreads();
    {
        const int h = lane >> 4, k = lane & 15;
        const int e = n * KK + k;
        float acc = 0.f;
        const unsigned short* kr = k0h + (size_t)e * 128 + h * 32;
#pragma unroll
        for (int c8 = 0; c8 < 4; ++c8) {
            s8v kv = ld8(kr + c8 * 8);
#pragma unroll
            for (int j = 0; j < 8; ++j)
                acc += q0s[wid][h * 32 + c8 * 8 + j] * bf2f((unsigned short)kv[j]);
        }
        s8v uv = ld8(uKh + (size_t)e * 32 + h * 8);
#pragma unroll
        for (int m = 0; m < 3; ++m) {
            float yv = y1[e * 3 + m];
            s8v k1v = ld8(k1ph + ((size_t)m * ENUM + e) * 32 + h * 8);
#pragma unroll
            for (int c = 0; c < 8; ++c)
                acc += q1s[wid][m * 32 + h * 8 + c] *
                       (bf2f((unsigned short)k1v[c]) + bf2f((unsigned short)uv[c]) * yv);
        }
        acc = acc * SCALE_ATTN + biasb[e * 4 + h];
        if (maskf[e] == 0.0f) acc = -1e9f;
        float mx = gmax16(acc);
        float ex = expf(acc - mx);
        float sm = gsum16(ex);
        attns[wid][lane] = ex / sm;
    }
    __syncthreads();
    const int g = lane & 15, kq = lane >> 4;
    {
        float o[8] = {};
        const float* aw = &attns[wid][(g >> 2) * 16];
#pragma unroll
        for (int kk2 = 0; kk2 < 4; ++kk2) {
            int kk = kq * 4 + kk2;
            float a = aw[kk];
            s8v v = ld8(v0h + (size_t)(n * KK + kk) * 128 + g * 8);
#pragma unroll
            for (int j = 0; j < 8; ++j) o[j] += a * bf2f((unsigned short)v[j]);
        }
#pragma unroll
        for (int j = 0; j < 8; ++j) {
            o[j] += __shfl_xor(o[j], 16);
            o[j] += __shfl_xor(o[j], 32);
        }
        if (kq == 0) {
            s8v r;
#pragma unroll
            for (int j = 0; j < 8; ++j) r[j] = (short)f2bf(o[j]);
            *(s8v*)&o0h[(size_t)n * 128 + g * 8] = r;
        }
    }
    {
        float o[8] = {};
        const int plane = g >> 2, cg = g & 3;
        if (g < 12) {
            const float* aw = &attns[wid][cg * 16];
#pragma unroll
            for (int kk2 = 0; kk2 < 4; ++kk2) {
                int kk = kq * 4 + kk2;
                int e2 = n * KK + kk;
                float a = aw[kk];
                float yv = y1[e2 * 3 + plane];
                s8v v = ld8(v1ph + ((size_t)plane * ENUM + e2) * 32 + cg * 8);
                s8v u = ld8(uVh + (size_t)e2 * 32 + cg * 8);
#pragma unroll
                for (int j = 0; j < 8; ++j)
                    o[j] += a * (bf2f((unsigned short)v[j]) + bf2f((unsigned short)u[j]) * yv);
            }
        }
#pragma unroll
        for (int j = 0; j < 8; ++j) {
            o[j] += __shfl_xor(o[j], 16);
            o[j] += __shfl_xor(o[j], 32);
        }
        if (kq == 0 && g < 12) {
            s8v r;
#pragma unroll
            for (int j = 0; j < 8; ++j) r[j] = (short)f2bf(o[j]);
            *(s8v*)&o1h[((size_t)plane * NN + n) * 32 + cg * 8] = r;
        }
    }
}

// =====================================================================
//  fused_post (512 threads, 8 waves): o-proj + residual + ff + residual,
//  then MODE0: next-layer fiber norm  or  MODE1: output projections.
// =====================================================================
template <int MODE>
__global__ __launch_bounds__(512) void fused_post(
    const unsigned short* __restrict__ o0h, const unsigned short* __restrict__ o1h,
    float* __restrict__ f0, float* __restrict__ f1p,
    const unsigned short* __restrict__ Wo0h, const unsigned short* __restrict__ Wo1h,
    const unsigned short* __restrict__ Wf0ah, const unsigned short* __restrict__ Wf0bh,
    const unsigned short* __restrict__ Wf1ah, const unsigned short* __restrict__ Wf1bh,
    const float* __restrict__ alA, const float* __restrict__ alF,
    const float* __restrict__ lnf0_g, const float* __restrict__ lnf0_b,
    const float* __restrict__ nf1_g, const float* __restrict__ nf1_b,
    const float* __restrict__ ln0n_g, const float* __restrict__ ln0n_b,
    const float* __restrict__ n1n_g, const float* __restrict__ n1n_b,
    unsigned short* __restrict__ x0h, unsigned short* __restrict__ x1h,
    const unsigned short* __restrict__ Wp0h, const float* __restrict__ Wp1,
    const float* __restrict__ coords, float* __restrict__ out) {
    __shared__ float f0s[16][132];
    __shared__ float f1s[3][16][36];
    __shared__ unsigned short x0s[16][136];
    __shared__ float x1s[3][16][36];
    __shared__ unsigned short hs[16][520];
    __shared__ unsigned short h1b[3][16][136];
    const int t = threadIdx.x, w = t >> 6, l = t & 63;
    const int c16 = l & 15, g8 = (l >> 4) * 8, g4 = (l >> 4) * 4;
    const int n0 = blockIdx.x * 16;
    const float aA = alA[0], aF = alF[0];

    {
        f4v acc = f4v{0.f, 0.f, 0.f, 0.f};
        const unsigned short* Ap = o0h + (size_t)(n0 + c16) * 128 + g8;
#pragma unroll
        for (int kc = 0; kc < 128; kc += 32) {
            s8v a = ld8(Ap + kc);
            s8v b = ld8(Wo0h + (size_t)(w * 16 + c16) * 128 + g8 + kc);
            acc = mfma16(a, b, acc);
        }
        int colg = w * 16 + c16;
#pragma unroll
        for (int r = 0; r < 4; ++r) {
            int row = g4 + r;
            f0s[row][colg] = f0[(size_t)(n0 + row) * 128 + colg] + aA * acc[r];
        }
    }
#pragma unroll
    for (int it = 0; it < 3; ++it) {
        int g = t + it * 512;
        int c = g & 31, node = (g >> 5) & 15, m = g >> 9;
        float a = 0.f;
        const unsigned short* wrow = Wo1h + c * 32;
        const unsigned short* orow = o1h + ((size_t)m * NN + n0 + node) * 32;
#pragma unroll
        for (int cc = 0; cc < 32; ++cc) a += bf2f(wrow[cc]) * bf2f(orow[cc]);
        f1s[m][node][c] = f1p[(size_t)m * PL + (n0 + node) * 32 + c] + aA * a;
    }
    __syncthreads();
    for (int i = 0; i < 2; ++i) {
        int row = w * 2 + i;
        float v0 = f0s[row][l], v1 = f0s[row][l + 64];
        float mn = wsum64(v0 + v1) * (1.0f / 128.0f);
        float d0 = v0 - mn, d1 = v1 - mn;
        float var = wsum64(d0 * d0 + d1 * d1) * (1.0f / 128.0f);
        float rs = rsqrtf(var + 1e-5f);
        x0s[row][l]      = f2bf(gelu_f(d0 * rs * lnf0_g[l] + lnf0_b[l]));
        x0s[row][l + 64] = f2bf(gelu_f(d1 * rs * lnf0_g[l + 64] + lnf0_b[l + 64]));
    }
    if (t < 256) {
        int node = t >> 4, sub = t & 15;
        float p[2][3], n1v[2];
#pragma unroll
        for (int q = 0; q < 2; ++q) {
            int c = sub + q * 16;
            p[q][0] = f1s[0][node][c]; p[q][1] = f1s[1][node][c]; p[q][2] = f1s[2][node][c];
            n1v[q] = sqrtf(p[q][0]*p[q][0] + p[q][1]*p[q][1] + p[q][2]*p[q][2]);
        }
        float s = gsum16(n1v[0] + n1v[1]);
        float mn = s * (1.0f / 32.0f);
        float d0 = n1v[0] - mn, d1 = n1v[1] - mn;
        float vv = gsum16(d0 * d0 + d1 * d1);
        float rs = rsqrtf(vv * (1.0f / 32.0f) + 1e-5f);
#pragma unroll
        for (int q = 0; q < 2; ++q) {
            int c = sub + q * 16;
            float sc = gelu_f((n1v[q] - mn) * rs * nf1_g[c] + nf1_b[c]) / (n1v[q] + 1e-6f);
            x1s[0][node][c] = p[q][0] * sc;
            x1s[1][node][c] = p[q][1] * sc;
            x1s[2][node][c] = p[q][2] * sc;
        }
    }
    __syncthreads();
    {
        f4v acc[4];
#pragma unroll
        for (int i = 0; i < 4; ++i) acc[i] = f4v{0.f,0.f,0.f,0.f};
#pragma unroll
        for (int kc = 0; kc < 128; kc += 32) {
            s8v a = *(const s8v*)&x0s[c16][kc + g8];
#pragma unroll
            for (int tt = 0; tt < 4; ++tt) {
                s8v b = ld8(Wf0ah + (size_t)((w * 4 + tt) * 16 + c16) * 128 + g8 + kc);
                acc[tt] = mfma16(a, b, acc[tt]);
            }
        }
#pragma unroll
        for (int tt = 0; tt < 4; ++tt) {
            int colg = (w * 4 + tt) * 16 + c16;
#pragma unroll
            for (int r = 0; r < 4; ++r) hs[g4 + r][colg] = f2bf(gelu_f(acc[tt][r]));
        }
    }
#pragma unroll
    for (int it = 0; it < 4; ++it) {
        int g = t + it * 512;
        int r = g & 127, node = g >> 7;
        float a0 = 0.f, a1 = 0.f, a2 = 0.f;
        const unsigned short* wrow = Wf1ah + r * 32;
#pragma unroll
        for (int c = 0; c < 32; ++c) {
            float wv = bf2f(wrow[c]);
            a0 += wv * x1s[0][node][c];
            a1 += wv * x1s[1][node][c];
            a2 += wv * x1s[2][node][c];
        }
        float nh = sqrtf(a0 * a0 + a1 * a1 + a2 * a2);
        float sc = gelu_f(nh) / (nh + 1e-6f);
        h1b[0][node][r] = f2bf(a0 * sc);
        h1b[1][node][r] = f2bf(a1 * sc);
        h1b[2][node][r] = f2bf(a2 * sc);
    }
    __syncthreads();
    {
        f4v acc = f4v{0.f, 0.f, 0.f, 0.f};
#pragma unroll 4
        for (int kc = 0; kc < 512; kc += 32) {
            s8v a = *(const s8v*)&hs[c16][kc + g8];
            s8v b = ld8(Wf0bh + (size_t)(w * 16 + c16) * 512 + g8 + kc);
            acc = mfma16(a, b, acc);
        }
        int colg = w * 16 + c16;
#pragma unroll
        for (int r = 0; r < 4; ++r) {
            int row = g4 + r;
            float v = f0s[row][colg] + aF * acc[r];
            f0s[row][colg] = v;
            f0[(size_t)(n0 + row) * 128 + colg] = v;
        }
    }
#pragma unroll
    for (int it = 0; it < 3; ++it) {
        int g = t + it * 512;
        int c = g & 31, node = (g >> 5) & 15, m = g >> 9;
        float a = 0.f;
        const unsigned short* wrow = Wf1bh + c * 128;
#pragma unroll 8
        for (int r = 0; r < 128; ++r) a += bf2f(wrow[r]) * bf2f(h1b[m][node][r]);
        float v = f1s[m][node][c] + aF * a;
        f1s[m][node][c] = v;
        f1p[(size_t)m * PL + (n0 + node) * 32 + c] = v;
    }
    __syncthreads();
    if (MODE == 0) {
        for (int i = 0; i < 2; ++i) {
            int row = w * 2 + i;
            float v0 = f0s[row][l], v1 = f0s[row][l + 64];
            float mn = wsum64(v0 + v1) * (1.0f / 128.0f);
            float d0 = v0 - mn, d1 = v1 - mn;
            float var = wsum64(d0 * d0 + d1 * d1) * (1.0f / 128.0f);
            float rs = rsqrtf(var + 1e-5f);
            x0h[(size_t)(n0 + row) * 128 + l]      = f2bf(gelu_f(d0 * rs * ln0n_g[l] + ln0n_b[l]));
            x0h[(size_t)(n0 + row) * 128 + l + 64] = f2bf(gelu_f(d1 * rs * ln0n_g[l + 64] + ln0n_b[l + 64]));
        }
        if (t < 256) {
            int node = t >> 4, sub = t & 15;
            float p[2][3], n1v[2];
#pragma unroll
            for (int q = 0; q < 2; ++q) {
                int c = sub + q * 16;
                p[q][0] = f1s[0][node][c]; p[q][1] = f1s[1][node][c]; p[q][2] = f1s[2][node][c];
                n1v[q] = sqrtf(p[q][0]*p[q][0] + p[q][1]*p[q][1] + p[q][2]*p[q][2]);
            }
            float s = gsum16(n1v[0] + n1v[1]);
            float mn = s * (1.0f / 32.0f);
            float d0 = n1v[0] - mn, d1 = n1v[1] - mn;
            float vv = gsum16(d0 * d0 + d1 * d1);
            float rs = rsqrtf(vv * (1.0f / 32.0f) + 1e-5f);
#pragma unroll
            for (int q = 0; q < 2; ++q) {
                int c = sub + q * 16;
                float sc = gelu_f((n1v[q] - mn) * rs * n1n_g[c] + n1n_b[c]) / (n1v[q] + 1e-6f);
                x1h[(size_t)0 * X1HS + (n0 + node) * 32 + c] = f2bf(p[q][0] * sc);
                x1h[(size_t)1 * X1HS + (n0 + node) * 32 + c] = f2bf(p[q][1] * sc);
                x1h[(size_t)2 * X1HS + (n0 + node) * 32 + c] = f2bf(p[q][2] * sc);
            }
        }
    } else {
#pragma unroll
        for (int it = 0; it < 4; ++it) {
            int g = t + it * 512;
            int row = g >> 7, col = g & 127;
            x0s[row][col] = f2bf(f0s[row][col]);
        }
        __syncthreads();
        f4v acc = f4v{0.f, 0.f, 0.f, 0.f};
#pragma unroll
        for (int kc = 0; kc < 128; kc += 32) {
            s8v a = *(const s8v*)&x0s[c16][kc + g8];
            s8v b = ld8(Wp0h + (size_t)(w * 16 + c16) * 128 + g8 + kc);
            acc = mfma16(a, b, acc);
        }
        int colg = w * 16 + c16;
#pragma unroll
        for (int r = 0; r < 4; ++r)
            out[(size_t)(n0 + g4 + r) * 128 + colg] = acc[r];
        if (t < 144) {
            int node = t / 9, rr = t % 9, o = rr / 3, m = rr % 3;
            float a = coords[((size_t)(n0 + node) * 4 + 1) * 3 + m];
            for (int c = 0; c < 32; ++c) a += Wp1[o * 32 + c] * f1s[m][node][c];
            out[NN * 128 + ((size_t)(n0 + node) * 3 + o) * 3 + m] = a;
        }
    }
}

extern "C" void kernel_launch(void* const* d_in, const int* in_sizes, int n_in,
                              void* d_out, int out_size, void* d_ws, size_t ws_size,
                              hipStream_t stream) {
    (void)in_sizes; (void)n_in; (void)out_size; (void)ws_size;
    const float* node_feats = (const float*)d_in[0];
    const float* pair       = (const float*)d_in[1];
    const float* coords     = (const float*)d_in[2];
    const float* eln_g      = (const float*)d_in[3];
    const float* eln_b      = (const float*)d_in[4];
    const float* Wi0        = (const float*)d_in[5];
    const float* Wi1        = (const float*)d_in[6];
    const float* ln0_g      = (const float*)d_in[7];
    const float* ln0_b      = (const float*)d_in[8];
    const float* n1_g       = (const float*)d_in[9];
    const float* n1_b       = (const float*)d_in[10];
    const float* Wq0        = (const float*)d_in[11];
    const float* Wq1        = (const float*)d_in[12];
    const float* WrK        = (const float*)d_in[13];
    const float* WrV        = (const float*)d_in[14];
    const float* WkA        = (const float*)d_in[15];
    const float* WkB        = (const float*)d_in[16];
    const float* WvA        = (const float*)d_in[17];
    const float* WvB        = (const float*)d_in[18];
    const float* Wb         = (const float*)d_in[19];
    const float* Wo0        = (const float*)d_in[20];
    const float* Wo1        = (const float*)d_in[21];
    const float* alpha_attn = (const float*)d_in[22];
    const float* lnf0_g     = (const float*)d_in[23];
    const float* lnf0_b     = (const float*)d_in[24];
    const float* nf1_g      = (const float*)d_in[25];
    const float* nf1_b      = (const float*)d_in[26];
    const float* Wf0a       = (const float*)d_in[27];
    const float* Wf0b       = (const float*)d_in[28];
    const float* Wf1a       = (const float*)d_in[29];
    const float* Wf1b       = (const float*)d_in[30];
    const float* alpha_ff   = (const float*)d_in[31];
    const float* Wp0        = (const float*)d_in[32];
    const float* Wp1        = (const float*)d_in[33];
    float* out = (float*)d_out;

    float* ws = (float*)d_ws;
    size_t off = 0;
    int*   idx   = (int*)(ws + off); off += NN * KK;
    float* maskf = ws + off;         off += NN * KK;
    float* y1    = ws + off;         off += NN * KK * 3;
    float* f0    = ws + off;         off += NN * C0c;
    float* f1p   = ws + off;         off += 3 * PL;
    float* q0    = ws + off;         off += NN * C0c;
    float* q1p   = ws + off;         off += 3 * PL;
    float* biasb = ws + off;         off += (size_t)ENUM * 4;
    off = (off + 3) & ~(size_t)3;
    unsigned short* up = (unsigned short*)(ws + off);
    size_t uo = 0;
    unsigned short* edges_h = up + uo; uo += (size_t)ENUM * 64;
    unsigned short* x0h     = up + uo; uo += (size_t)NN * 128;
    unsigned short* x1h     = up + uo; uo += (size_t)3 * X1HS;
    unsigned short* nf_h    = up + uo; uo += (size_t)NN * 128;
    unsigned short* k0h     = up + uo; uo += (size_t)ENUM * 128;
    unsigned short* v0h     = up + uo; uo += (size_t)ENUM * 128;
    unsigned short* uKh     = up + uo; uo += (size_t)ENUM * 32;
    unsigned short* uVh     = up + uo; uo += (size_t)ENUM * 32;
    unsigned short* k1ph    = up + uo; uo += (size_t)3 * ENUM * 32;
    unsigned short* v1ph    = up + uo; uo += (size_t)3 * ENUM * 32;
    unsigned short* o0h     = up + uo; uo += (size_t)NN * 128;
    unsigned short* o1h     = up + uo; uo += (size_t)3 * NN * 32;
    unsigned short* WrK_h   = up + uo; uo += 2 * 24576;
    unsigned short* WrV_h   = up + uo; uo += 2 * 24576;
    unsigned short* WkA_h   = up + uo; uo += 2 * 20480;
    unsigned short* WvA_h   = up + uo; uo += 2 * 20480;
    unsigned short* WkB_h   = up + uo; uo += 2 * 7168;
    unsigned short* WvB_h   = up + uo; uo += 2 * 7168;
    unsigned short* Wq0_h   = up + uo; uo += 2 * 16384;
    unsigned short* Wq1_h   = up + uo; uo += 2 * 1024;
    unsigned short* Wo0_h   = up + uo; uo += 2 * 16384;
    unsigned short* Wo1_h   = up + uo; uo += 2 * 1024;
    unsigned short* Wf0a_h  = up + uo; uo += 2 * 65536;
    unsigned short* Wf0b_h  = up + uo; uo += 2 * 65536;
    unsigned short* Wf1a_h  = up + uo; uo += 2 * 4096;
    unsigned short* Wf1b_h  = up + uo; uo += 2 * 4096;
    unsigned short* Wp0_h   = up + uo; uo += 16384;
    unsigned short* Wi0_h   = up + uo; uo += 16384;
    unsigned short* Wb_h    = up + uo; uo += 2 * 256;

    CvJobs cj; cj.n = 18;
    cj.j[0]  = {WrK,  WrK_h,  2 * 24576};
    cj.j[1]  = {WrV,  WrV_h,  2 * 24576};
    cj.j[2]  = {WkA,  WkA_h,  2 * 20480};
    cj.j[3]  = {WvA,  WvA_h,  2 * 20480};
    cj.j[4]  = {WkB,  WkB_h,  2 * 7168};
    cj.j[5]  = {WvB,  WvB_h,  2 * 7168};
    cj.j[6]  = {Wq0,  Wq0_h,  2 * 16384};
    cj.j[7]  = {Wq1,  Wq1_h,  2 * 1024};
    cj.j[8]  = {Wo0,  Wo0_h,  2 * 16384};
    cj.j[9]  = {Wo1,  Wo1_h,  2 * 1024};
    cj.j[10] = {Wf0a, Wf0a_h, 2 * 65536};
    cj.j[11] = {Wf0b, Wf0b_h, 2 * 65536};
    cj.j[12] = {Wf1a, Wf1a_h, 2 * 4096};
    cj.j[13] = {Wf1b, Wf1b_h, 2 * 4096};
    cj.j[14] = {Wp0,  Wp0_h,  16384};
    cj.j[15] = {Wi0,  Wi0_h,  16384};
    cj.j[16] = {node_feats, nf_h, NN * 128};
    cj.j[17] = {Wb,   Wb_h,   2 * 256};
    cj.total = 2*24576*2 + 2*20480*2 + 2*7168*2 + 2*16384 + 2*1024 + 2*16384
             + 2*1024 + 2*65536*2 + 2*4096*2 + 16384 + 16384 + NN*128 + 2*256;
    const int cvb = (cj.total + 255) / 256;

    setup_kernel<<<cvb + 256 + 128, 256, 0, stream>>>(cj, cvb, coords, idx, maskf, y1, Wi1, f1p);
    edge_f0_kernel<<<ENUM / 4 + 32, 256, 0, stream>>>(pair, idx, eln_g, eln_b,
                                                      edges_h, nf_h, Wi0_h, f0);
    fnorm1_kernel<<<NN / 4, 256, 0, stream>>>(f0, f1p, ln0_g, ln0_b, n1_g, n1_b, x0h, x1h);

    for (int l = 0; l < Lc; ++l) {
        edge_kv2<<<284, 512, EKV_LDS2, stream>>>(
            edges_h,
            WrK_h + (size_t)l * 24576, WrV_h + (size_t)l * 24576,
            WkA_h + (size_t)l * 20480, WvA_h + (size_t)l * 20480,
            WkB_h + (size_t)l * 7168,  WvB_h + (size_t)l * 7168,
            Wb_h + (size_t)l * 256,
            x0h, x1h, idx, y1,
            k0h, v0h, uKh, uVh, k1ph, v1ph, biasb,
            Wq0_h + (size_t)l * 16384, Wq1_h + (size_t)l * 1024, q0, q1p);
        attn_core<<<NN / 4, 256, 0, stream>>>(q0, q1p, k0h, k1ph, v0h, v1ph, uKh, uVh,
            biasb, maskf, y1, o0h, o1h);
        if (l == 0) {
            fused_post<0><<<NN / 16, 512, 0, stream>>>(
                o0h, o1h, f0, f1p,
                Wo0_h, Wo1_h, Wf0a_h, Wf0b_h, Wf1a_h, Wf1b_h,
                alpha_attn + 0, alpha_ff + 0,
                lnf0_g, lnf0_b, nf1_g, nf1_b,
                ln0_g + 128, ln0_b + 128, n1_g + 32, n1_b + 32,
                x0h, x1h, nullptr, nullptr, nullptr, nullptr);
        } else {
            fused_post<1><<<NN / 16, 512, 0, stream>>>(
                o0h, o1h, f0, f1p,
                Wo0_h + 16384, Wo1_h + 1024, Wf0a_h + 65536, Wf0b_h + 65536,
                Wf1a_h + 4096, Wf1b_h + 4096,
                alpha_attn + 1, alpha_ff + 1,
                lnf0_g + 128, lnf0_b + 128, nf1_g + 32, nf1_b + 32,
                nullptr, nullptr, nullptr, nullptr,
                nullptr, nullptr, Wp0_h, Wp1, coords, out);
        }
    }
}